// Round 1
// baseline (1018.960 us; speedup 1.0000x reference)
//
#include <hip/hip_runtime.h>
#include <hip/hip_bf16.h>

// Problem constants
#define B_   8
#define N_   1024
#define M_   128
#define C_   1024
#define H_   16
#define D_   64
#define MLP_ 4096

typedef __bf16 bf16;
typedef __bf16 bf16x8 __attribute__((ext_vector_type(8)));
typedef __bf16 bf16x4 __attribute__((ext_vector_type(4)));
typedef float  f32x4  __attribute__((ext_vector_type(4)));

__device__ __forceinline__ f32x4 mfma16(bf16x8 a, bf16x8 b, f32x4 c) {
    return __builtin_amdgcn_mfma_f32_16x16x32_bf16(a, b, c, 0, 0, 0);
}

// ---------------------------------------------------------------------------
// Weight transpose + fp32->bf16 convert:  W (K x Nc) fp32  ->  Wt (Nc x K) bf16
// ---------------------------------------------------------------------------
__global__ __launch_bounds__(256) void transpose_k(const float* __restrict__ W,
                                                   bf16* __restrict__ Wt,
                                                   int K, int Nc) {
    __shared__ float tile[32][33];
    const int x  = threadIdx.x & 31;
    const int y0 = threadIdx.x >> 5;           // 0..7
    const size_t n0 = (size_t)blockIdx.x * 32;
    const size_t k0 = (size_t)blockIdx.y * 32;
#pragma unroll
    for (int i = 0; i < 4; i++)
        tile[y0 + i * 8][x] = W[(k0 + y0 + i * 8) * Nc + n0 + x];
    __syncthreads();
#pragma unroll
    for (int i = 0; i < 4; i++)
        Wt[(n0 + y0 + i * 8) * K + k0 + x] = (bf16)tile[x][y0 + i * 8];
}

// fp32 -> bf16 elementwise (n4 = count/4)
__global__ __launch_bounds__(256) void cvt_bf16_k(const float* __restrict__ in,
                                                  bf16* __restrict__ out, int n4) {
    int i = blockIdx.x * 256 + threadIdx.x;
    if (i < n4) {
        float4 v = ((const float4*)in)[i];
        bf16x4 o;
        o[0] = (bf16)v.x; o[1] = (bf16)v.y; o[2] = (bf16)v.z; o[3] = (bf16)v.w;
        ((bf16x4*)out)[i] = o;
    }
}

// ---------------------------------------------------------------------------
// ada = silu(c_dino) @ W_ada + b_ada      (8 x 6144), fp32
// grid 24 blocks x 256 threads; each thread computes one col for all 8 batches
// ---------------------------------------------------------------------------
__global__ __launch_bounds__(256) void ada_k(const float* __restrict__ cdino,
                                             const float* __restrict__ W,
                                             const float* __restrict__ bias,
                                             float* __restrict__ ada) {
    __shared__ float sc[8][1024];   // 32 KB
    const int tid = threadIdx.x;
    for (int i = tid; i < 8 * 1024; i += 256) {
        float c = cdino[i];
        sc[i >> 10][i & 1023] = c / (1.f + __expf(-c));
    }
    __syncthreads();
    const int col = blockIdx.x * 256 + tid;
    float acc[8];
#pragma unroll
    for (int b = 0; b < 8; b++) acc[b] = bias[col];
    for (int k = 0; k < 1024; k++) {
        float w = W[(size_t)k * 6144 + col];
#pragma unroll
        for (int b = 0; b < 8; b++) acc[b] += sc[b][k] * w;
    }
#pragma unroll
    for (int b = 0; b < 8; b++) ada[(size_t)b * 6144 + col] = acc[b];
}

// ---------------------------------------------------------------------------
// h = modulate(LN(x), shift, scale)  -> bf16    one block per row of 1024
// ---------------------------------------------------------------------------
__global__ __launch_bounds__(256) void ln_mod_k(const float* __restrict__ X,
                                                const float* __restrict__ ada,
                                                int shoff, int scoff,
                                                bf16* __restrict__ Hout) {
    const int row = blockIdx.x;           // 0..8191
    const int b   = row >> 10;
    const int tid = threadIdx.x;
    const float4 v = ((const float4*)(X + (size_t)row * C_))[tid];
    float s  = v.x + v.y + v.z + v.w;
    float sq = v.x * v.x + v.y * v.y + v.z * v.z + v.w * v.w;
#pragma unroll
    for (int off = 32; off; off >>= 1) {
        s  += __shfl_xor(s,  off);
        sq += __shfl_xor(sq, off);
    }
    __shared__ float rs_[4], rq_[4];
    if ((tid & 63) == 0) { rs_[tid >> 6] = s; rq_[tid >> 6] = sq; }
    __syncthreads();
    s  = rs_[0] + rs_[1] + rs_[2] + rs_[3];
    sq = rq_[0] + rq_[1] + rq_[2] + rq_[3];
    const float mu   = s * (1.f / 1024.f);
    const float var  = sq * (1.f / 1024.f) - mu * mu;
    const float rstd = rsqrtf(var + 1e-6f);
    const float4 scv = ((const float4*)(ada + (size_t)b * 6144 + scoff))[tid];
    const float4 shv = ((const float4*)(ada + (size_t)b * 6144 + shoff))[tid];
    bf16x4 o;
    o[0] = (bf16)(((v.x - mu) * rstd) * (1.f + scv.x) + shv.x);
    o[1] = (bf16)(((v.y - mu) * rstd) * (1.f + scv.y) + shv.y);
    o[2] = (bf16)(((v.z - mu) * rstd) * (1.f + scv.z) + shv.z);
    o[3] = (bf16)(((v.w - mu) * rstd) * (1.f + scv.w) + shv.w);
    *(bf16x4*)(Hout + (size_t)row * C_ + tid * 4) = o;
}

// ---------------------------------------------------------------------------
// Generic bf16 MFMA GEMM:  out(M x N) = A(M x K) @ Bt(N x K)^T + bias
// 256 threads, 128x128 tile, BK=32, 4 waves each computing 64x64 (4x4 frags).
// MODE 1: fp32 out = v + resid   (resid may alias outF, same-index)
// MODE 2: bf16 out = v
// MODE 3: bf16 out = gelu_tanh(v)
// ---------------------------------------------------------------------------
template <int MODE>
__global__ __launch_bounds__(256) void gemm_k(const bf16* __restrict__ A,
                                              const bf16* __restrict__ Bt,
                                              const float* __restrict__ bias,
                                              const float* resid,
                                              float* outF, bf16* outB,
                                              int Ncols, int K) {
    __shared__ __attribute__((aligned(16))) bf16 As[128][40];  // stride 40: 2-way banks, 16B-aligned
    __shared__ __attribute__((aligned(16))) bf16 Bs[128][40];
    const int tid  = threadIdx.x;
    const int lane = tid & 63, wave = tid >> 6;
    const int lrow = lane & 15, quad = lane >> 4;
    const int wm = wave >> 1, wn = wave & 1;
    const size_t bm = (size_t)blockIdx.y * 128;
    const size_t bn = (size_t)blockIdx.x * 128;

    const int srow = tid >> 1, sseg = tid & 1;
    const bf16* gA = A  + (bm + srow) * (size_t)K + sseg * 16;
    const bf16* gB = Bt + (bn + srow) * (size_t)K + sseg * 16;

    f32x4 acc[4][4];
#pragma unroll
    for (int i = 0; i < 4; i++)
#pragma unroll
        for (int j = 0; j < 4; j++) acc[i][j] = (f32x4){0.f, 0.f, 0.f, 0.f};

    for (int ko = 0; ko < K; ko += 32) {
        __syncthreads();
        bf16x8 a0 = *(const bf16x8*)(gA + ko);
        bf16x8 a1 = *(const bf16x8*)(gA + ko + 8);
        bf16x8 b0 = *(const bf16x8*)(gB + ko);
        bf16x8 b1 = *(const bf16x8*)(gB + ko + 8);
        *(bf16x8*)&As[srow][sseg * 16]     = a0;
        *(bf16x8*)&As[srow][sseg * 16 + 8] = a1;
        *(bf16x8*)&Bs[srow][sseg * 16]     = b0;
        *(bf16x8*)&Bs[srow][sseg * 16 + 8] = b1;
        __syncthreads();
        bf16x8 af[4], bfr[4];
#pragma unroll
        for (int mi = 0; mi < 4; mi++)
            af[mi] = *(const bf16x8*)&As[wm * 64 + mi * 16 + lrow][quad * 8];
#pragma unroll
        for (int ni = 0; ni < 4; ni++)
            bfr[ni] = *(const bf16x8*)&Bs[wn * 64 + ni * 16 + lrow][quad * 8];
#pragma unroll
        for (int mi = 0; mi < 4; mi++)
#pragma unroll
            for (int ni = 0; ni < 4; ni++)
                acc[mi][ni] = mfma16(af[mi], bfr[ni], acc[mi][ni]);
    }

#pragma unroll
    for (int mi = 0; mi < 4; mi++) {
#pragma unroll
        for (int ni = 0; ni < 4; ni++) {
            const size_t gcol = bn + wn * 64 + ni * 16 + lrow;
            const float bv = bias[gcol];
#pragma unroll
            for (int r = 0; r < 4; r++) {
                const size_t grow = bm + wm * 64 + mi * 16 + quad * 4 + r;
                const size_t idx  = grow * Ncols + gcol;
                float v = acc[mi][ni][r] + bv;
                if (MODE == 1) {
                    outF[idx] = v + resid[idx];
                } else if (MODE == 2) {
                    outB[idx] = (bf16)v;
                } else {
                    float g = 0.5f * v * (1.f + tanhf(0.79788456f * (v + 0.044715f * v * v * v)));
                    outB[idx] = (bf16)g;
                }
            }
        }
    }
}

// ---------------------------------------------------------------------------
// Flash attention (bf16 MFMA 16x16x32), D=64, key chunks of 64.
// grid (N/64, H, B), 256 threads = 4 waves; each wave owns 16 query rows.
// Q from Qp (row = b*N + n, col = h*64+d), K/V from KVp (row = b*Mk + m).
// Online softmax in C-layout; P->A-layout via LDS round trip (m120 pattern).
// ---------------------------------------------------------------------------
template <bool MASKED>
__global__ __launch_bounds__(256) void attn_k(const bf16* __restrict__ Qp, int qstride,
                                              const bf16* __restrict__ KVp, int kvstride,
                                              int koff, int voff,
                                              const int* __restrict__ mask, int Mk,
                                              bf16* __restrict__ O) {
    __shared__ __attribute__((aligned(16))) bf16 Kt[64][88];      // [key][d]   11.3 KB
    __shared__ __attribute__((aligned(16))) bf16 Vt[64][88];      // [d][key]   11.3 KB
    __shared__ __attribute__((aligned(16))) bf16 Pt[4][16][88];   // per wave [q][key]
    __shared__ float madd[64];

    const int b = blockIdx.z, h = blockIdx.y;
    const int tid  = threadIdx.x;
    const int lane = tid & 63, wave = tid >> 6;
    const int lrow = lane & 15, quad = lane >> 4;
    const int q0 = blockIdx.x * 64 + wave * 16;

    // Q A-fragments (m = lane&15, k = quad*8+j [+32])
    const bf16* qp = Qp + ((size_t)(b * N_ + q0 + lrow)) * qstride + h * 64 + quad * 8;
    const bf16x8 aq0 = *(const bf16x8*)(qp);
    const bf16x8 aq1 = *(const bf16x8*)(qp + 32);

    f32x4 acc[4];
#pragma unroll
    for (int t = 0; t < 4; t++) acc[t] = (f32x4){0.f, 0.f, 0.f, 0.f};
    float mrun[4], lrun[4];
#pragma unroll
    for (int r = 0; r < 4; r++) { mrun[r] = -3e38f; lrun[r] = 0.f; }

    const int skey = tid >> 2;           // 0..63
    const int sd   = (tid & 3) * 16;     // 0,16,32,48

    for (int kc = 0; kc < Mk; kc += 64) {
        __syncthreads();
        // stage K row-major [key][d]
        const bf16* kp = KVp + ((size_t)(b * Mk + kc + skey)) * kvstride + koff + h * 64 + sd;
        bf16x8 k0 = *(const bf16x8*)kp;
        bf16x8 k1 = *(const bf16x8*)(kp + 8);
        *(bf16x8*)&Kt[skey][sd]     = k0;
        *(bf16x8*)&Kt[skey][sd + 8] = k1;
        // stage V transposed [d][key]
        const bf16* vp = KVp + ((size_t)(b * Mk + kc + skey)) * kvstride + voff + h * 64 + sd;
        bf16x8 v0 = *(const bf16x8*)vp;
        bf16x8 v1 = *(const bf16x8*)(vp + 8);
#pragma unroll
        for (int i = 0; i < 8; i++) Vt[sd + i][skey] = v0[i];
#pragma unroll
        for (int i = 0; i < 8; i++) Vt[sd + 8 + i][skey] = v1[i];
        if (MASKED && tid < 64)
            madd[tid] = (mask[b * Mk + kc + tid] == 0) ? -1e30f : 0.f;
        __syncthreads();

        // S = Q K^T  (rows=q in C-layout, cols=key)
        float sv[4][4];
#pragma unroll
        for (int t = 0; t < 4; t++) {
            f32x4 s = (f32x4){0.f, 0.f, 0.f, 0.f};
            bf16x8 bk0 = *(const bf16x8*)&Kt[t * 16 + lrow][quad * 8];
            s = mfma16(aq0, bk0, s);
            bf16x8 bk1 = *(const bf16x8*)&Kt[t * 16 + lrow][32 + quad * 8];
            s = mfma16(aq1, bk1, s);
            const float ma = MASKED ? madd[t * 16 + lrow] : 0.f;
#pragma unroll
            for (int r = 0; r < 4; r++) sv[t][r] = s[r] * 0.125f + ma;
        }

        // online softmax (row r lives in the 16 lanes of this quad)
        float pv[4][4], alpha[4];
#pragma unroll
        for (int r = 0; r < 4; r++) {
            float vmax = fmaxf(fmaxf(sv[0][r], sv[1][r]), fmaxf(sv[2][r], sv[3][r]));
#pragma unroll
            for (int off = 1; off < 16; off <<= 1) vmax = fmaxf(vmax, __shfl_xor(vmax, off));
            const float mnew = fmaxf(mrun[r], vmax);
            alpha[r] = __expf(mrun[r] - mnew);
            mrun[r] = mnew;
            float rsum = 0.f;
#pragma unroll
            for (int t = 0; t < 4; t++) {
                float p = __expf(sv[t][r] - mnew);
                pv[t][r] = p;
                rsum += p;
            }
#pragma unroll
            for (int off = 1; off < 16; off <<= 1) rsum += __shfl_xor(rsum, off);
            lrun[r] = lrun[r] * alpha[r] + rsum;
        }
#pragma unroll
        for (int t = 0; t < 4; t++)
#pragma unroll
            for (int r = 0; r < 4; r++) acc[t][r] *= alpha[r];

        // P: C-layout -> LDS -> A-layout
#pragma unroll
        for (int t = 0; t < 4; t++)
#pragma unroll
            for (int r = 0; r < 4; r++)
                Pt[wave][quad * 4 + r][t * 16 + lrow] = (bf16)pv[t][r];
        __syncthreads();
        const bf16x8 ap0 = *(const bf16x8*)&Pt[wave][lrow][quad * 8];
        const bf16x8 ap1 = *(const bf16x8*)&Pt[wave][lrow][32 + quad * 8];

        // O += P V
#pragma unroll
        for (int t = 0; t < 4; t++) {
            bf16x8 bv0 = *(const bf16x8*)&Vt[t * 16 + lrow][quad * 8];
            acc[t] = mfma16(ap0, bv0, acc[t]);
            bf16x8 bv1 = *(const bf16x8*)&Vt[t * 16 + lrow][32 + quad * 8];
            acc[t] = mfma16(ap1, bv1, acc[t]);
        }
    }

    // epilogue: O /= l, write bf16 (B*N x C)
#pragma unroll
    for (int r = 0; r < 4; r++) {
        const float inv = 1.f / lrun[r];
        const size_t grow = (size_t)(b * N_ + q0 + quad * 4 + r);
#pragma unroll
        for (int t = 0; t < 4; t++)
            O[grow * C_ + h * 64 + t * 16 + lrow] = (bf16)(acc[t][r] * inv);
    }
}

// ---------------------------------------------------------------------------
extern "C" void kernel_launch(void* const* d_in, const int* in_sizes, int n_in,
                              void* d_out, int out_size, void* d_ws, size_t ws_size,
                              hipStream_t stream) {
    const float* x     = (const float*)d_in[0];
    const float* cdino = (const float*)d_in[1];
    const float* ctext = (const float*)d_in[2];
    const int*   tmask = (const int*)d_in[3];
    const float* W_ada = (const float*)d_in[4];
    const float* b_ada = (const float*)d_in[5];
    const float* W_qkv = (const float*)d_in[6];
    const float* b_qkv = (const float*)d_in[7];
    const float* W_sa  = (const float*)d_in[8];
    const float* b_sa  = (const float*)d_in[9];
    const float* W_q   = (const float*)d_in[10];
    const float* b_q   = (const float*)d_in[11];
    const float* W_kv  = (const float*)d_in[12];
    const float* b_kv  = (const float*)d_in[13];
    const float* W_ca  = (const float*)d_in[14];
    const float* b_ca  = (const float*)d_in[15];
    const float* W_fc1 = (const float*)d_in[16];
    const float* b_fc1 = (const float*)d_in[17];
    const float* W_fc2 = (const float*)d_in[18];
    const float* b_fc2 = (const float*)d_in[19];
    float* out = (float*)d_out;

    char* ws = (char*)d_ws;
    size_t off = 0;
    auto alloc = [&](size_t bytes) -> char* {
        char* p = ws + off;
        off += (bytes + 255) & ~(size_t)255;
        return p;
    };
    float* ada  = (float*)alloc((size_t)8 * 6144 * 4);
    bf16* ctxb  = (bf16*)alloc((size_t)1024 * 1024 * 2);
    bf16* WqkvT = (bf16*)alloc((size_t)3072 * 1024 * 2);
    bf16* WsaT  = (bf16*)alloc((size_t)1024 * 1024 * 2);
    bf16* WqT   = (bf16*)alloc((size_t)1024 * 1024 * 2);
    bf16* WkvT  = (bf16*)alloc((size_t)2048 * 1024 * 2);
    bf16* WcaT  = (bf16*)alloc((size_t)1024 * 1024 * 2);
    bf16* Wfc1T = (bf16*)alloc((size_t)4096 * 1024 * 2);
    bf16* Wfc2T = (bf16*)alloc((size_t)1024 * 4096 * 2);
    float* xbuf = (float*)alloc((size_t)8192 * 1024 * 4);
    bf16* hbuf  = (bf16*)alloc((size_t)8192 * 1024 * 2);
    bf16* attnb = (bf16*)alloc((size_t)8192 * 1024 * 2);
    bf16* pool  = (bf16*)alloc((size_t)8192 * 4096 * 2);  // qkv | q+kv | gelu
    if (off > ws_size) return;  // insufficient workspace -> fail loudly

    bf16* qkvb  = pool;
    bf16* qb    = pool;
    bf16* kvb   = pool + (size_t)8192 * 1024;
    bf16* gelub = pool;

    // --- weight prep (bf16, transposed) ---
    transpose_k<<<dim3(3072 / 32, 1024 / 32), 256, 0, stream>>>(W_qkv, WqkvT, 1024, 3072);
    transpose_k<<<dim3(1024 / 32, 1024 / 32), 256, 0, stream>>>(W_sa,  WsaT,  1024, 1024);
    transpose_k<<<dim3(1024 / 32, 1024 / 32), 256, 0, stream>>>(W_q,   WqT,   1024, 1024);
    transpose_k<<<dim3(2048 / 32, 1024 / 32), 256, 0, stream>>>(W_kv,  WkvT,  1024, 2048);
    transpose_k<<<dim3(1024 / 32, 1024 / 32), 256, 0, stream>>>(W_ca,  WcaT,  1024, 1024);
    transpose_k<<<dim3(4096 / 32, 1024 / 32), 256, 0, stream>>>(W_fc1, Wfc1T, 1024, 4096);
    transpose_k<<<dim3(1024 / 32, 4096 / 32), 256, 0, stream>>>(W_fc2, Wfc2T, 4096, 1024);
    cvt_bf16_k<<<1024, 256, 0, stream>>>(ctext, ctxb, 262144);

    // --- ada ---
    ada_k<<<24, 256, 0, stream>>>(cdino, W_ada, b_ada, ada);

    // --- self-attention ---
    ln_mod_k<<<8192, 256, 0, stream>>>(x, ada, 0, 1024, hbuf);
    gemm_k<2><<<dim3(24, 64), 256, 0, stream>>>(hbuf, WqkvT, b_qkv, nullptr, nullptr, qkvb, 3072, 1024);
    attn_k<false><<<dim3(16, 16, 8), 256, 0, stream>>>(qkvb, 3072, qkvb, 3072, 1024, 2048,
                                                       nullptr, 1024, attnb);
    gemm_k<1><<<dim3(8, 64), 256, 0, stream>>>(attnb, WsaT, b_sa, x, xbuf, nullptr, 1024, 1024);

    // --- cross-attention ---
    ln_mod_k<<<8192, 256, 0, stream>>>(xbuf, ada, 2048, 3072, hbuf);
    gemm_k<2><<<dim3(8, 64), 256, 0, stream>>>(hbuf, WqT, b_q, nullptr, nullptr, qb, 1024, 1024);
    gemm_k<2><<<dim3(16, 8), 256, 0, stream>>>(ctxb, WkvT, b_kv, nullptr, nullptr, kvb, 2048, 1024);
    attn_k<true><<<dim3(16, 16, 8), 256, 0, stream>>>(qb, 1024, kvb, 2048, 0, 1024,
                                                      tmask, 128, attnb);
    gemm_k<1><<<dim3(8, 64), 256, 0, stream>>>(attnb, WcaT, b_ca, xbuf, xbuf, nullptr, 1024, 1024);

    // --- MLP ---
    ln_mod_k<<<8192, 256, 0, stream>>>(xbuf, ada, 4096, 5120, hbuf);
    gemm_k<3><<<dim3(32, 64), 256, 0, stream>>>(hbuf, Wfc1T, b_fc1, nullptr, nullptr, gelub, 4096, 1024);
    gemm_k<1><<<dim3(8, 64), 256, 0, stream>>>(gelub, Wfc2T, b_fc2, xbuf, out, nullptr, 1024, 4096);
}

// Round 2
// 825.332 us; speedup vs baseline: 1.2346x; 1.2346x over previous
//
#include <hip/hip_runtime.h>
#include <hip/hip_bf16.h>

// Problem constants
#define B_   8
#define N_   1024
#define M_   128
#define C_   1024
#define H_   16
#define D_   64
#define MLP_ 4096

typedef __bf16 bf16;
typedef __bf16 bf16x8 __attribute__((ext_vector_type(8)));
typedef __bf16 bf16x4 __attribute__((ext_vector_type(4)));
typedef float  f32x4  __attribute__((ext_vector_type(4)));

__device__ __forceinline__ f32x4 mfma16(bf16x8 a, bf16x8 b, f32x4 c) {
    return __builtin_amdgcn_mfma_f32_16x16x32_bf16(a, b, c, 0, 0, 0);
}

// async global->LDS, 16 B per lane. LDS dest must be wave-uniform base;
// HW scatters lane i to base + i*16.
__device__ __forceinline__ void gload16(const bf16* g, bf16* l) {
    __builtin_amdgcn_global_load_lds(
        (const __attribute__((address_space(1))) void*)g,
        (__attribute__((address_space(3))) void*)l, 16, 0, 0);
}

// ---------------------------------------------------------------------------
// Weight transpose + fp32->bf16 convert:  W (K x Nc) fp32  ->  Wt (Nc x K) bf16
// ---------------------------------------------------------------------------
__global__ __launch_bounds__(256) void transpose_k(const float* __restrict__ W,
                                                   bf16* __restrict__ Wt,
                                                   int K, int Nc) {
    __shared__ float tile[32][33];
    const int x  = threadIdx.x & 31;
    const int y0 = threadIdx.x >> 5;           // 0..7
    const size_t n0 = (size_t)blockIdx.x * 32;
    const size_t k0 = (size_t)blockIdx.y * 32;
#pragma unroll
    for (int i = 0; i < 4; i++)
        tile[y0 + i * 8][x] = W[(k0 + y0 + i * 8) * Nc + n0 + x];
    __syncthreads();
#pragma unroll
    for (int i = 0; i < 4; i++)
        Wt[(n0 + y0 + i * 8) * K + k0 + x] = (bf16)tile[x][y0 + i * 8];
}

// fp32 -> bf16 elementwise (n4 = count/4)
__global__ __launch_bounds__(256) void cvt_bf16_k(const float* __restrict__ in,
                                                  bf16* __restrict__ out, int n4) {
    int i = blockIdx.x * 256 + threadIdx.x;
    if (i < n4) {
        float4 v = ((const float4*)in)[i];
        bf16x4 o;
        o[0] = (bf16)v.x; o[1] = (bf16)v.y; o[2] = (bf16)v.z; o[3] = (bf16)v.w;
        ((bf16x4*)out)[i] = o;
    }
}

// ---------------------------------------------------------------------------
// ada = silu(c_dino) @ W_ada + b_ada   (8 x 6144) fp32, split-K with atomics.
// ada must be pre-initialized to bias (ada_init_k). grid (24, 32) x 256.
// ---------------------------------------------------------------------------
__global__ __launch_bounds__(256) void ada_init_k(const float* __restrict__ bias,
                                                  float* __restrict__ ada) {
    int i = blockIdx.x * 256 + threadIdx.x;   // 49152 total
    ada[i] = bias[i % 6144];
}

__global__ __launch_bounds__(256) void ada_k(const float* __restrict__ cdino,
                                             const float* __restrict__ W,
                                             float* __restrict__ ada) {
    __shared__ float sc[8][32];
    const int tid = threadIdx.x;
    const int k0  = blockIdx.y * 32;
    {
        float c = cdino[(tid >> 5) * 1024 + k0 + (tid & 31)];
        sc[tid >> 5][tid & 31] = c / (1.f + __expf(-c));
    }
    __syncthreads();
    const int col = blockIdx.x * 256 + tid;
    float acc[8];
#pragma unroll
    for (int b = 0; b < 8; b++) acc[b] = 0.f;
    for (int kk = 0; kk < 32; kk++) {
        float w = W[(size_t)(k0 + kk) * 6144 + col];
#pragma unroll
        for (int b = 0; b < 8; b++) acc[b] += sc[b][kk] * w;
    }
#pragma unroll
    for (int b = 0; b < 8; b++) atomicAdd(&ada[(size_t)b * 6144 + col], acc[b]);
}

// ---------------------------------------------------------------------------
// h = modulate(LN(x), shift, scale)  -> bf16    one block per row of 1024
// ---------------------------------------------------------------------------
__global__ __launch_bounds__(256) void ln_mod_k(const float* __restrict__ X,
                                                const float* __restrict__ ada,
                                                int shoff, int scoff,
                                                bf16* __restrict__ Hout) {
    const int row = blockIdx.x;           // 0..8191
    const int b   = row >> 10;
    const int tid = threadIdx.x;
    const float4 v = ((const float4*)(X + (size_t)row * C_))[tid];
    float s  = v.x + v.y + v.z + v.w;
    float sq = v.x * v.x + v.y * v.y + v.z * v.z + v.w * v.w;
#pragma unroll
    for (int off = 32; off; off >>= 1) {
        s  += __shfl_xor(s,  off);
        sq += __shfl_xor(sq, off);
    }
    __shared__ float rs_[4], rq_[4];
    if ((tid & 63) == 0) { rs_[tid >> 6] = s; rq_[tid >> 6] = sq; }
    __syncthreads();
    s  = rs_[0] + rs_[1] + rs_[2] + rs_[3];
    sq = rq_[0] + rq_[1] + rq_[2] + rq_[3];
    const float mu   = s * (1.f / 1024.f);
    const float var  = sq * (1.f / 1024.f) - mu * mu;
    const float rstd = rsqrtf(var + 1e-6f);
    const float4 scv = ((const float4*)(ada + (size_t)b * 6144 + scoff))[tid];
    const float4 shv = ((const float4*)(ada + (size_t)b * 6144 + shoff))[tid];
    bf16x4 o;
    o[0] = (bf16)(((v.x - mu) * rstd) * (1.f + scv.x) + shv.x);
    o[1] = (bf16)(((v.y - mu) * rstd) * (1.f + scv.y) + shv.y);
    o[2] = (bf16)(((v.z - mu) * rstd) * (1.f + scv.z) + shv.z);
    o[3] = (bf16)(((v.w - mu) * rstd) * (1.f + scv.w) + shv.w);
    *(bf16x4*)(Hout + (size_t)row * C_ + tid * 4) = o;
}

// ---------------------------------------------------------------------------
// Generic bf16 MFMA GEMM (m97 structure):  out(M x N) = A(M x K) @ Bt(N x K)^T + bias
// 256 threads, 128x128 tile, BK=32, global_load_lds dwordx4 staging into
// unpadded LDS; 4 waves each 64x64 (4x4 16x16x32 frags); 2-barrier K-loop.
// MODE 1: fp32 out = v + resid    MODE 2: bf16 out = v    MODE 3: bf16 gelu(v)
// ---------------------------------------------------------------------------
template <int MODE>
__global__ __launch_bounds__(256) void gemm_k(const bf16* __restrict__ A,
                                              const bf16* __restrict__ Bt,
                                              const float* __restrict__ bias,
                                              const float* resid,
                                              float* outF, bf16* outB,
                                              int Ncols, int K) {
    __shared__ __attribute__((aligned(16))) bf16 As[128][32];  // 8 KB, unpadded (glds layout)
    __shared__ __attribute__((aligned(16))) bf16 Bs[128][32];
    const int tid  = threadIdx.x;
    const int lane = tid & 63, wave = tid >> 6;
    const int lrow = lane & 15, quad = lane >> 4;
    const int wm = wave >> 1, wn = wave & 1;
    const size_t bm = (size_t)blockIdx.y * 128;
    const size_t bn = (size_t)blockIdx.x * 128;

    // staging map: thread tid covers LDS bytes [tid*16, tid*16+16) of each
    // 64-row half-tile; i.e. row = tid>>2 (+64), k-seg = (tid&3)*8
    const int srow = tid >> 2, sseg = tid & 3;
    const bf16* gA0 = A  + (bm + srow) * (size_t)K + sseg * 8;
    const bf16* gA1 = gA0 + (size_t)64 * K;
    const bf16* gB0 = Bt + (bn + srow) * (size_t)K + sseg * 8;
    const bf16* gB1 = gB0 + (size_t)64 * K;
    bf16* lA0 = &As[0][0] + wave * 512;   // wave-uniform: wave*1024 bytes
    bf16* lA1 = lA0 + 2048;               // +4096 bytes (rows 64..127)
    bf16* lB0 = &Bs[0][0] + wave * 512;
    bf16* lB1 = lB0 + 2048;

    f32x4 acc[4][4];
#pragma unroll
    for (int i = 0; i < 4; i++)
#pragma unroll
        for (int j = 0; j < 4; j++) acc[i][j] = (f32x4){0.f, 0.f, 0.f, 0.f};

    for (int ko = 0; ko < K; ko += 32) {
        gload16(gA0 + ko, lA0);
        gload16(gA1 + ko, lA1);
        gload16(gB0 + ko, lB0);
        gload16(gB1 + ko, lB1);
        __syncthreads();           // drains vmcnt -> LDS tiles visible
        bf16x8 af[4], bfr[4];
#pragma unroll
        for (int mi = 0; mi < 4; mi++)
            af[mi] = *(const bf16x8*)&As[wm * 64 + mi * 16 + lrow][quad * 8];
#pragma unroll
        for (int ni = 0; ni < 4; ni++)
            bfr[ni] = *(const bf16x8*)&Bs[wn * 64 + ni * 16 + lrow][quad * 8];
#pragma unroll
        for (int mi = 0; mi < 4; mi++)
#pragma unroll
            for (int ni = 0; ni < 4; ni++)
                acc[mi][ni] = mfma16(af[mi], bfr[ni], acc[mi][ni]);
        __syncthreads();           // protect LDS before next iter's overwrite
    }

#pragma unroll
    for (int mi = 0; mi < 4; mi++) {
#pragma unroll
        for (int ni = 0; ni < 4; ni++) {
            const size_t gcol = bn + wn * 64 + ni * 16 + lrow;
            const float bv = bias[gcol];
#pragma unroll
            for (int r = 0; r < 4; r++) {
                const size_t grow = bm + wm * 64 + mi * 16 + quad * 4 + r;
                const size_t idx  = grow * Ncols + gcol;
                float v = acc[mi][ni][r] + bv;
                if (MODE == 1) {
                    outF[idx] = v + resid[idx];
                } else if (MODE == 2) {
                    outB[idx] = (bf16)v;
                } else {
                    // gelu_tanh(v) == v * sigmoid(1.59576912*(v+0.044715*v^3))
                    float z = 1.59576912f * (v + 0.044715f * v * v * v);
                    outB[idx] = (bf16)(v / (1.f + __expf(-z)));
                }
            }
        }
    }
}

// ---------------------------------------------------------------------------
// Flash attention (bf16 MFMA 16x16x32), D=64, key chunks of 64.
// grid (N/64, H, B), 256 threads = 4 waves; each wave owns 16 query rows.
// ---------------------------------------------------------------------------
template <bool MASKED>
__global__ __launch_bounds__(256) void attn_k(const bf16* __restrict__ Qp, int qstride,
                                              const bf16* __restrict__ KVp, int kvstride,
                                              int koff, int voff,
                                              const int* __restrict__ mask, int Mk,
                                              bf16* __restrict__ O) {
    __shared__ __attribute__((aligned(16))) bf16 Kt[64][88];      // [key][d]
    __shared__ __attribute__((aligned(16))) bf16 Vt[64][88];      // [d][key]
    __shared__ __attribute__((aligned(16))) bf16 Pt[4][16][88];   // per wave [q][key]
    __shared__ float madd[64];

    const int b = blockIdx.z, h = blockIdx.y;
    const int tid  = threadIdx.x;
    const int lane = tid & 63, wave = tid >> 6;
    const int lrow = lane & 15, quad = lane >> 4;
    const int q0 = blockIdx.x * 64 + wave * 16;

    const bf16* qp = Qp + ((size_t)(b * N_ + q0 + lrow)) * qstride + h * 64 + quad * 8;
    const bf16x8 aq0 = *(const bf16x8*)(qp);
    const bf16x8 aq1 = *(const bf16x8*)(qp + 32);

    f32x4 acc[4];
#pragma unroll
    for (int t = 0; t < 4; t++) acc[t] = (f32x4){0.f, 0.f, 0.f, 0.f};
    float mrun[4], lrun[4];
#pragma unroll
    for (int r = 0; r < 4; r++) { mrun[r] = -3e38f; lrun[r] = 0.f; }

    const int skey = tid >> 2;           // 0..63
    const int sd   = (tid & 3) * 16;     // 0,16,32,48

    for (int kc = 0; kc < Mk; kc += 64) {
        __syncthreads();
        const bf16* kp = KVp + ((size_t)(b * Mk + kc + skey)) * kvstride + koff + h * 64 + sd;
        bf16x8 k0 = *(const bf16x8*)kp;
        bf16x8 k1 = *(const bf16x8*)(kp + 8);
        *(bf16x8*)&Kt[skey][sd]     = k0;
        *(bf16x8*)&Kt[skey][sd + 8] = k1;
        const bf16* vp = KVp + ((size_t)(b * Mk + kc + skey)) * kvstride + voff + h * 64 + sd;
        bf16x8 v0 = *(const bf16x8*)vp;
        bf16x8 v1 = *(const bf16x8*)(vp + 8);
#pragma unroll
        for (int i = 0; i < 8; i++) Vt[sd + i][skey] = v0[i];
#pragma unroll
        for (int i = 0; i < 8; i++) Vt[sd + 8 + i][skey] = v1[i];
        if (MASKED && tid < 64)
            madd[tid] = (mask[b * Mk + kc + tid] == 0) ? -1e30f : 0.f;
        __syncthreads();

        float sv[4][4];
#pragma unroll
        for (int t = 0; t < 4; t++) {
            f32x4 s = (f32x4){0.f, 0.f, 0.f, 0.f};
            bf16x8 bk0 = *(const bf16x8*)&Kt[t * 16 + lrow][quad * 8];
            s = mfma16(aq0, bk0, s);
            bf16x8 bk1 = *(const bf16x8*)&Kt[t * 16 + lrow][32 + quad * 8];
            s = mfma16(aq1, bk1, s);
            const float ma = MASKED ? madd[t * 16 + lrow] : 0.f;
#pragma unroll
            for (int r = 0; r < 4; r++) sv[t][r] = s[r] * 0.125f + ma;
        }

        float pv[4][4], alpha[4];
#pragma unroll
        for (int r = 0; r < 4; r++) {
            float vmax = fmaxf(fmaxf(sv[0][r], sv[1][r]), fmaxf(sv[2][r], sv[3][r]));
#pragma unroll
            for (int off = 1; off < 16; off <<= 1) vmax = fmaxf(vmax, __shfl_xor(vmax, off));
            const float mnew = fmaxf(mrun[r], vmax);
            alpha[r] = __expf(mrun[r] - mnew);
            mrun[r] = mnew;
            float rsum = 0.f;
#pragma unroll
            for (int t = 0; t < 4; t++) {
                float p = __expf(sv[t][r] - mnew);
                pv[t][r] = p;
                rsum += p;
            }
#pragma unroll
            for (int off = 1; off < 16; off <<= 1) rsum += __shfl_xor(rsum, off);
            lrun[r] = lrun[r] * alpha[r] + rsum;
        }
#pragma unroll
        for (int t = 0; t < 4; t++)
#pragma unroll
            for (int r = 0; r < 4; r++) acc[t][r] *= alpha[r];

#pragma unroll
        for (int t = 0; t < 4; t++)
#pragma unroll
            for (int r = 0; r < 4; r++)
                Pt[wave][quad * 4 + r][t * 16 + lrow] = (bf16)pv[t][r];
        __syncthreads();
        const bf16x8 ap0 = *(const bf16x8*)&Pt[wave][lrow][quad * 8];
        const bf16x8 ap1 = *(const bf16x8*)&Pt[wave][lrow][32 + quad * 8];

#pragma unroll
        for (int t = 0; t < 4; t++) {
            bf16x8 bv0 = *(const bf16x8*)&Vt[t * 16 + lrow][quad * 8];
            acc[t] = mfma16(ap0, bv0, acc[t]);
            bf16x8 bv1 = *(const bf16x8*)&Vt[t * 16 + lrow][32 + quad * 8];
            acc[t] = mfma16(ap1, bv1, acc[t]);
        }
    }

#pragma unroll
    for (int r = 0; r < 4; r++) {
        const float inv = 1.f / lrun[r];
        const size_t grow = (size_t)(b * N_ + q0 + quad * 4 + r);
#pragma unroll
        for (int t = 0; t < 4; t++)
            O[grow * C_ + h * 64 + t * 16 + lrow] = (bf16)(acc[t][r] * inv);
    }
}

// ---------------------------------------------------------------------------
extern "C" void kernel_launch(void* const* d_in, const int* in_sizes, int n_in,
                              void* d_out, int out_size, void* d_ws, size_t ws_size,
                              hipStream_t stream) {
    const float* x     = (const float*)d_in[0];
    const float* cdino = (const float*)d_in[1];
    const float* ctext = (const float*)d_in[2];
    const int*   tmask = (const int*)d_in[3];
    const float* W_ada = (const float*)d_in[4];
    const float* b_ada = (const float*)d_in[5];
    const float* W_qkv = (const float*)d_in[6];
    const float* b_qkv = (const float*)d_in[7];
    const float* W_sa  = (const float*)d_in[8];
    const float* b_sa  = (const float*)d_in[9];
    const float* W_q   = (const float*)d_in[10];
    const float* b_q   = (const float*)d_in[11];
    const float* W_kv  = (const float*)d_in[12];
    const float* b_kv  = (const float*)d_in[13];
    const float* W_ca  = (const float*)d_in[14];
    const float* b_ca  = (const float*)d_in[15];
    const float* W_fc1 = (const float*)d_in[16];
    const float* b_fc1 = (const float*)d_in[17];
    const float* W_fc2 = (const float*)d_in[18];
    const float* b_fc2 = (const float*)d_in[19];
    float* out = (float*)d_out;

    char* ws = (char*)d_ws;
    size_t off = 0;
    auto alloc = [&](size_t bytes) -> char* {
        char* p = ws + off;
        off += (bytes + 255) & ~(size_t)255;
        return p;
    };
    float* ada  = (float*)alloc((size_t)8 * 6144 * 4);
    bf16* ctxb  = (bf16*)alloc((size_t)1024 * 1024 * 2);
    bf16* WqkvT = (bf16*)alloc((size_t)3072 * 1024 * 2);
    bf16* WsaT  = (bf16*)alloc((size_t)1024 * 1024 * 2);
    bf16* WqT   = (bf16*)alloc((size_t)1024 * 1024 * 2);
    bf16* WkvT  = (bf16*)alloc((size_t)2048 * 1024 * 2);
    bf16* WcaT  = (bf16*)alloc((size_t)1024 * 1024 * 2);
    bf16* Wfc1T = (bf16*)alloc((size_t)4096 * 1024 * 2);
    bf16* Wfc2T = (bf16*)alloc((size_t)1024 * 4096 * 2);
    float* xbuf = (float*)alloc((size_t)8192 * 1024 * 4);
    bf16* hbuf  = (bf16*)alloc((size_t)8192 * 1024 * 2);
    bf16* attnb = (bf16*)alloc((size_t)8192 * 1024 * 2);
    bf16* pool  = (bf16*)alloc((size_t)8192 * 4096 * 2);  // qkv | q+kv | gelu
    if (off > ws_size) return;

    bf16* qkvb  = pool;
    bf16* qb    = pool;
    bf16* kvb   = pool + (size_t)8192 * 1024;
    bf16* gelub = pool;

    // --- weight prep (bf16, transposed) ---
    transpose_k<<<dim3(3072 / 32, 1024 / 32), 256, 0, stream>>>(W_qkv, WqkvT, 1024, 3072);
    transpose_k<<<dim3(1024 / 32, 1024 / 32), 256, 0, stream>>>(W_sa,  WsaT,  1024, 1024);
    transpose_k<<<dim3(1024 / 32, 1024 / 32), 256, 0, stream>>>(W_q,   WqT,   1024, 1024);
    transpose_k<<<dim3(2048 / 32, 1024 / 32), 256, 0, stream>>>(W_kv,  WkvT,  1024, 2048);
    transpose_k<<<dim3(1024 / 32, 1024 / 32), 256, 0, stream>>>(W_ca,  WcaT,  1024, 1024);
    transpose_k<<<dim3(4096 / 32, 1024 / 32), 256, 0, stream>>>(W_fc1, Wfc1T, 1024, 4096);
    transpose_k<<<dim3(1024 / 32, 4096 / 32), 256, 0, stream>>>(W_fc2, Wfc2T, 4096, 1024);
    cvt_bf16_k<<<1024, 256, 0, stream>>>(ctext, ctxb, 262144);

    // --- ada (split-K + atomics) ---
    ada_init_k<<<192, 256, 0, stream>>>(b_ada, ada);
    ada_k<<<dim3(24, 32), 256, 0, stream>>>(cdino, W_ada, ada);

    // --- self-attention ---
    ln_mod_k<<<8192, 256, 0, stream>>>(x, ada, 0, 1024, hbuf);
    gemm_k<2><<<dim3(24, 64), 256, 0, stream>>>(hbuf, WqkvT, b_qkv, nullptr, nullptr, qkvb, 3072, 1024);
    attn_k<false><<<dim3(16, 16, 8), 256, 0, stream>>>(qkvb, 3072, qkvb, 3072, 1024, 2048,
                                                       nullptr, 1024, attnb);
    gemm_k<1><<<dim3(8, 64), 256, 0, stream>>>(attnb, WsaT, b_sa, x, xbuf, nullptr, 1024, 1024);

    // --- cross-attention ---
    ln_mod_k<<<8192, 256, 0, stream>>>(xbuf, ada, 2048, 3072, hbuf);
    gemm_k<2><<<dim3(8, 64), 256, 0, stream>>>(hbuf, WqT, b_q, nullptr, nullptr, qb, 1024, 1024);
    gemm_k<2><<<dim3(16, 8), 256, 0, stream>>>(ctxb, WkvT, b_kv, nullptr, nullptr, kvb, 2048, 1024);
    attn_k<true><<<dim3(16, 16, 8), 256, 0, stream>>>(qb, 1024, kvb, 2048, 0, 1024,
                                                      tmask, 128, attnb);
    gemm_k<1><<<dim3(8, 64), 256, 0, stream>>>(attnb, WcaT, b_ca, xbuf, xbuf, nullptr, 1024, 1024);

    // --- MLP ---
    ln_mod_k<<<8192, 256, 0, stream>>>(xbuf, ada, 4096, 5120, hbuf);
    gemm_k<3><<<dim3(32, 64), 256, 0, stream>>>(hbuf, Wfc1T, b_fc1, nullptr, nullptr, gelub, 4096, 1024);
    gemm_k<1><<<dim3(8, 64), 256, 0, stream>>>(gelub, Wfc2T, b_fc2, xbuf, out, nullptr, 1024, 4096);
}

// Round 3
// 790.711 us; speedup vs baseline: 1.2887x; 1.0438x over previous
//
#include <hip/hip_runtime.h>
#include <hip/hip_bf16.h>

// Problem constants
#define B_   8
#define N_   1024
#define M_   128
#define C_   1024
#define H_   16
#define D_   64
#define MLP_ 4096

typedef __bf16 bf16;
typedef __bf16 bf16x8 __attribute__((ext_vector_type(8)));
typedef __bf16 bf16x4 __attribute__((ext_vector_type(4)));
typedef float  f32x4  __attribute__((ext_vector_type(4)));

__device__ __forceinline__ f32x4 mfma16(bf16x8 a, bf16x8 b, f32x4 c) {
    return __builtin_amdgcn_mfma_f32_16x16x32_bf16(a, b, c, 0, 0, 0);
}

// async global->LDS, 16 B per lane (LDS dest wave-uniform base + lane*16)
__device__ __forceinline__ void gload16(const bf16* g, bf16* l) {
    __builtin_amdgcn_global_load_lds(
        (const __attribute__((address_space(1))) void*)g,
        (__attribute__((address_space(3))) void*)l, 16, 0, 0);
}

// ---------------------------------------------------------------------------
// Weight transpose + fp32->bf16:  W (K x Nc) fp32  ->  Wt (Nc x K) bf16
// ---------------------------------------------------------------------------
__global__ __launch_bounds__(256) void transpose_k(const float* __restrict__ W,
                                                   bf16* __restrict__ Wt,
                                                   int K, int Nc) {
    __shared__ float tile[32][33];
    const int x  = threadIdx.x & 31;
    const int y0 = threadIdx.x >> 5;
    const size_t n0 = (size_t)blockIdx.x * 32;
    const size_t k0 = (size_t)blockIdx.y * 32;
#pragma unroll
    for (int i = 0; i < 4; i++)
        tile[y0 + i * 8][x] = W[(k0 + y0 + i * 8) * Nc + n0 + x];
    __syncthreads();
#pragma unroll
    for (int i = 0; i < 4; i++)
        Wt[(n0 + y0 + i * 8) * K + k0 + x] = (bf16)tile[x][y0 + i * 8];
}

// bf16 V transpose: in rows (b*Mk + m), cols coff+hd (hd=h*64+d, 1024 wide)
//                -> outT[(b*1024 + hd) * Mk + m]
__global__ __launch_bounds__(256) void vtrans_k(const bf16* __restrict__ in, int instride,
                                                int coff, int Mk, bf16* __restrict__ outT) {
    __shared__ bf16 t[32][33];
    const int tx = threadIdx.x & 31;
    const int ty0 = threadIdx.x >> 5;
    const int m0  = blockIdx.x * 32;
    const int hd0 = blockIdx.y * 32;
    const int b   = blockIdx.z;
#pragma unroll
    for (int i = 0; i < 4; i++)
        t[ty0 + i * 8][tx] = in[((size_t)(b * Mk + m0 + ty0 + i * 8)) * instride + coff + hd0 + tx];
    __syncthreads();
#pragma unroll
    for (int i = 0; i < 4; i++)
        outT[((size_t)(b * 1024 + hd0 + ty0 + i * 8)) * Mk + m0 + tx] = t[tx][ty0 + i * 8];
}

// fp32 -> bf16 elementwise (n4 = count/4)
__global__ __launch_bounds__(256) void cvt_bf16_k(const float* __restrict__ in,
                                                  bf16* __restrict__ out, int n4) {
    int i = blockIdx.x * 256 + threadIdx.x;
    if (i < n4) {
        float4 v = ((const float4*)in)[i];
        bf16x4 o;
        o[0] = (bf16)v.x; o[1] = (bf16)v.y; o[2] = (bf16)v.z; o[3] = (bf16)v.w;
        ((bf16x4*)out)[i] = o;
    }
}

// ---------------------------------------------------------------------------
// ada = silu(c_dino) @ W_ada + b_ada   (8 x 6144) fp32, split-K with atomics.
// ---------------------------------------------------------------------------
__global__ __launch_bounds__(256) void ada_init_k(const float* __restrict__ bias,
                                                  float* __restrict__ ada) {
    int i = blockIdx.x * 256 + threadIdx.x;
    ada[i] = bias[i % 6144];
}

__global__ __launch_bounds__(256) void ada_k(const float* __restrict__ cdino,
                                             const float* __restrict__ W,
                                             float* __restrict__ ada) {
    __shared__ float sc[8][32];
    const int tid = threadIdx.x;
    const int k0  = blockIdx.y * 32;
    {
        float c = cdino[(tid >> 5) * 1024 + k0 + (tid & 31)];
        sc[tid >> 5][tid & 31] = c / (1.f + __expf(-c));
    }
    __syncthreads();
    const int col = blockIdx.x * 256 + tid;
    float acc[8];
#pragma unroll
    for (int b = 0; b < 8; b++) acc[b] = 0.f;
    for (int kk = 0; kk < 32; kk++) {
        float w = W[(size_t)(k0 + kk) * 6144 + col];
#pragma unroll
        for (int b = 0; b < 8; b++) acc[b] += sc[b][kk] * w;
    }
#pragma unroll
    for (int b = 0; b < 8; b++) atomicAdd(&ada[(size_t)b * 6144 + col], acc[b]);
}

// ---------------------------------------------------------------------------
// h = modulate(LN(x), shift, scale)  -> bf16
// ---------------------------------------------------------------------------
__global__ __launch_bounds__(256) void ln_mod_k(const float* __restrict__ X,
                                                const float* __restrict__ ada,
                                                int shoff, int scoff,
                                                bf16* __restrict__ Hout) {
    const int row = blockIdx.x;
    const int b   = row >> 10;
    const int tid = threadIdx.x;
    const float4 v = ((const float4*)(X + (size_t)row * C_))[tid];
    float s  = v.x + v.y + v.z + v.w;
    float sq = v.x * v.x + v.y * v.y + v.z * v.z + v.w * v.w;
#pragma unroll
    for (int off = 32; off; off >>= 1) {
        s  += __shfl_xor(s,  off);
        sq += __shfl_xor(sq, off);
    }
    __shared__ float rs_[4], rq_[4];
    if ((tid & 63) == 0) { rs_[tid >> 6] = s; rq_[tid >> 6] = sq; }
    __syncthreads();
    s  = rs_[0] + rs_[1] + rs_[2] + rs_[3];
    sq = rq_[0] + rq_[1] + rq_[2] + rq_[3];
    const float mu   = s * (1.f / 1024.f);
    const float var  = sq * (1.f / 1024.f) - mu * mu;
    const float rstd = rsqrtf(var + 1e-6f);
    const float4 scv = ((const float4*)(ada + (size_t)b * 6144 + scoff))[tid];
    const float4 shv = ((const float4*)(ada + (size_t)b * 6144 + shoff))[tid];
    bf16x4 o;
    o[0] = (bf16)(((v.x - mu) * rstd) * (1.f + scv.x) + shv.x);
    o[1] = (bf16)(((v.y - mu) * rstd) * (1.f + scv.y) + shv.y);
    o[2] = (bf16)(((v.z - mu) * rstd) * (1.f + scv.z) + shv.z);
    o[3] = (bf16)(((v.w - mu) * rstd) * (1.f + scv.w) + shv.w);
    *(bf16x4*)(Hout + (size_t)row * C_ + tid * 4) = o;
}

// ---------------------------------------------------------------------------
// Generic bf16 MFMA GEMM (m97 structure), 128x128 tile, BK=32.
// ---------------------------------------------------------------------------
template <int MODE>
__global__ __launch_bounds__(256) void gemm_k(const bf16* __restrict__ A,
                                              const bf16* __restrict__ Bt,
                                              const float* __restrict__ bias,
                                              const float* resid,
                                              float* outF, bf16* outB,
                                              int Ncols, int K) {
    __shared__ __attribute__((aligned(16))) bf16 As[128][32];
    __shared__ __attribute__((aligned(16))) bf16 Bs[128][32];
    const int tid  = threadIdx.x;
    const int lane = tid & 63, wave = tid >> 6;
    const int lrow = lane & 15, quad = lane >> 4;
    const int wm = wave >> 1, wn = wave & 1;
    const size_t bm = (size_t)blockIdx.y * 128;
    const size_t bn = (size_t)blockIdx.x * 128;

    const int srow = tid >> 2, sseg = tid & 3;
    const bf16* gA0 = A  + (bm + srow) * (size_t)K + sseg * 8;
    const bf16* gA1 = gA0 + (size_t)64 * K;
    const bf16* gB0 = Bt + (bn + srow) * (size_t)K + sseg * 8;
    const bf16* gB1 = gB0 + (size_t)64 * K;
    bf16* lA0 = &As[0][0] + wave * 512;
    bf16* lA1 = lA0 + 2048;
    bf16* lB0 = &Bs[0][0] + wave * 512;
    bf16* lB1 = lB0 + 2048;

    f32x4 acc[4][4];
#pragma unroll
    for (int i = 0; i < 4; i++)
#pragma unroll
        for (int j = 0; j < 4; j++) acc[i][j] = (f32x4){0.f, 0.f, 0.f, 0.f};

    for (int ko = 0; ko < K; ko += 32) {
        gload16(gA0 + ko, lA0);
        gload16(gA1 + ko, lA1);
        gload16(gB0 + ko, lB0);
        gload16(gB1 + ko, lB1);
        __syncthreads();
        bf16x8 af[4], bfr[4];
#pragma unroll
        for (int mi = 0; mi < 4; mi++)
            af[mi] = *(const bf16x8*)&As[wm * 64 + mi * 16 + lrow][quad * 8];
#pragma unroll
        for (int ni = 0; ni < 4; ni++)
            bfr[ni] = *(const bf16x8*)&Bs[wn * 64 + ni * 16 + lrow][quad * 8];
#pragma unroll
        for (int mi = 0; mi < 4; mi++)
#pragma unroll
            for (int ni = 0; ni < 4; ni++)
                acc[mi][ni] = mfma16(af[mi], bfr[ni], acc[mi][ni]);
        __syncthreads();
    }

#pragma unroll
    for (int mi = 0; mi < 4; mi++) {
#pragma unroll
        for (int ni = 0; ni < 4; ni++) {
            const size_t gcol = bn + wn * 64 + ni * 16 + lrow;
            const float bv = bias[gcol];
#pragma unroll
            for (int r = 0; r < 4; r++) {
                const size_t grow = bm + wm * 64 + mi * 16 + quad * 4 + r;
                const size_t idx  = grow * Ncols + gcol;
                float v = acc[mi][ni][r] + bv;
                if (MODE == 1) {
                    outF[idx] = v + resid[idx];
                } else if (MODE == 2) {
                    outB[idx] = (bf16)v;
                } else {
                    float z = 1.59576912f * (v + 0.044715f * v * v * v);
                    outB[idx] = (bf16)(v / (1.f + __expf(-z)));
                }
            }
        }
    }
}

// ---------------------------------------------------------------------------
// Flash attention, S^T formulation. D=64, 64-key chunks.
// grid (N/64, H, B), 4 waves; wave owns 16 q-rows.
// S^T = K·Q^T (A=K vector reads, B=Q regs). Softmax per-lane (q=lane&15):
// in-lane over 16 keys + shfl_xor(16,32) across quads. P stored [q][key]
// (packed b64 writes), consumed as A-frag; V^T (pre-transposed in global)
// staged row-major as B-frag. O rows = quad*4+r, cols d = t*16 + lane&15.
// ---------------------------------------------------------------------------
template <bool MASKED>
__global__ __launch_bounds__(256) void attn_k(const bf16* __restrict__ Qp, int qstride,
                                              const bf16* __restrict__ Kp, int kstride,
                                              const bf16* __restrict__ Vtg,
                                              const int* __restrict__ mask, int Mk,
                                              bf16* __restrict__ O) {
    __shared__ __attribute__((aligned(16))) bf16 Kt[64][88];      // [key][d]
    __shared__ __attribute__((aligned(16))) bf16 Vt[64][88];      // [d][key]
    __shared__ __attribute__((aligned(16))) bf16 Pt[4][16][88];   // [wave][q][key]
    __shared__ float madd[64];

    const int b = blockIdx.z, h = blockIdx.y;
    const int tid  = threadIdx.x;
    const int lane = tid & 63, wave = tid >> 6;
    const int lrow = lane & 15, quad = lane >> 4;
    const int q0 = blockIdx.x * 64 + wave * 16;

    // Q fragment (B-operand for S^T): row q0+lrow, cols quad*8.. (+32)
    const bf16* qp = Qp + ((size_t)(b * N_ + q0 + lrow)) * qstride + h * 64 + quad * 8;
    const bf16x8 bq0 = *(const bf16x8*)(qp);
    const bf16x8 bq1 = *(const bf16x8*)(qp + 32);

    f32x4 acc[4];
#pragma unroll
    for (int t = 0; t < 4; t++) acc[t] = (f32x4){0.f, 0.f, 0.f, 0.f};
    float mrun = -3e38f, lrun = 0.f;   // per-lane state for q = lrow

    const int srow = tid >> 2;           // 0..63
    const int sseg = (tid & 3) * 16;     // 0,16,32,48

    const bf16* kbase = Kp + ((size_t)b * Mk + srow) * kstride + h * 64 + sseg;
    const bf16* vbase = Vtg + ((size_t)(b * 1024 + h * 64 + srow)) * Mk + sseg;

    for (int kc = 0; kc < Mk; kc += 64) {
        __syncthreads();
        // stage K row-major [key][d]
        const bf16* kp = kbase + (size_t)kc * kstride;
        bf16x8 k0 = *(const bf16x8*)kp;
        bf16x8 k1 = *(const bf16x8*)(kp + 8);
        *(bf16x8*)&Kt[srow][sseg]     = k0;
        *(bf16x8*)&Kt[srow][sseg + 8] = k1;
        // stage V^T row-major [d][key] (already transposed in global)
        const bf16* vp = vbase + kc;
        bf16x8 v0 = *(const bf16x8*)vp;
        bf16x8 v1 = *(const bf16x8*)(vp + 8);
        *(bf16x8*)&Vt[srow][sseg]     = v0;
        *(bf16x8*)&Vt[srow][sseg + 8] = v1;
        if (MASKED && tid < 64)
            madd[tid] = (mask[b * Mk + kc + tid] == 0) ? -1e30f : 0.f;
        __syncthreads();

        // S^T tiles: rows key = t*16+quad*4+r, cols q = lrow
        float sv[4][4];
#pragma unroll
        for (int t = 0; t < 4; t++) {
            f32x4 s = (f32x4){0.f, 0.f, 0.f, 0.f};
            bf16x8 ak0 = *(const bf16x8*)&Kt[t * 16 + lrow][quad * 8];
            s = mfma16(ak0, bq0, s);
            bf16x8 ak1 = *(const bf16x8*)&Kt[t * 16 + lrow][32 + quad * 8];
            s = mfma16(ak1, bq1, s);
#pragma unroll
            for (int r = 0; r < 4; r++) {
                float ma = MASKED ? madd[t * 16 + quad * 4 + r] : 0.f;
                sv[t][r] = s[r] * 0.125f + ma;
            }
        }

        // online softmax, per-lane state (q = lrow)
        float vmax = sv[0][0];
#pragma unroll
        for (int t = 0; t < 4; t++)
#pragma unroll
            for (int r = 0; r < 4; r++) vmax = fmaxf(vmax, sv[t][r]);
        vmax = fmaxf(vmax, __shfl_xor(vmax, 16));
        vmax = fmaxf(vmax, __shfl_xor(vmax, 32));
        const float mnew  = fmaxf(mrun, vmax);
        const float alpha = __expf(mrun - mnew);
        mrun = mnew;
        float rsum = 0.f;
#pragma unroll
        for (int t = 0; t < 4; t++) {
            bf16x4 p4;
#pragma unroll
            for (int r = 0; r < 4; r++) {
                float p = __expf(sv[t][r] - mnew);
                rsum += p;
                p4[r] = (bf16)p;
            }
            *(bf16x4*)&Pt[wave][lrow][t * 16 + quad * 4] = p4;  // P[q][key], b64
        }
        rsum += __shfl_xor(rsum, 16);
        rsum += __shfl_xor(rsum, 32);
        lrun = lrun * alpha + rsum;

        // rescale O-acc: rows are q = quad*4+r -> fetch alpha from lane quad*4+r
        float alpha4[4];
#pragma unroll
        for (int r = 0; r < 4; r++) alpha4[r] = __shfl(alpha, quad * 4 + r);
#pragma unroll
        for (int t = 0; t < 4; t++)
#pragma unroll
            for (int r = 0; r < 4; r++) acc[t][r] *= alpha4[r];

        __syncthreads();   // Pt visibility (also orders vs. next staging)
        const bf16x8 ap0 = *(const bf16x8*)&Pt[wave][lrow][quad * 8];
        const bf16x8 ap1 = *(const bf16x8*)&Pt[wave][lrow][32 + quad * 8];

        // O += P V : A=P, B=V (from V^T rows)
#pragma unroll
        for (int t = 0; t < 4; t++) {
            bf16x8 bv0 = *(const bf16x8*)&Vt[t * 16 + lrow][quad * 8];
            acc[t] = mfma16(ap0, bv0, acc[t]);
            bf16x8 bv1 = *(const bf16x8*)&Vt[t * 16 + lrow][32 + quad * 8];
            acc[t] = mfma16(ap1, bv1, acc[t]);
        }
    }

    // epilogue: O rows q = quad*4+r, cols d = t*16+lrow
    float linv = 1.f / lrun;
    float linv4[4];
#pragma unroll
    for (int r = 0; r < 4; r++) linv4[r] = __shfl(linv, quad * 4 + r);
#pragma unroll
    for (int r = 0; r < 4; r++) {
        const size_t grow = (size_t)(b * N_ + q0 + quad * 4 + r);
#pragma unroll
        for (int t = 0; t < 4; t++)
            O[grow * C_ + h * 64 + t * 16 + lrow] = (bf16)(acc[t][r] * linv4[r]);
    }
}

// ---------------------------------------------------------------------------
extern "C" void kernel_launch(void* const* d_in, const int* in_sizes, int n_in,
                              void* d_out, int out_size, void* d_ws, size_t ws_size,
                              hipStream_t stream) {
    const float* x     = (const float*)d_in[0];
    const float* cdino = (const float*)d_in[1];
    const float* ctext = (const float*)d_in[2];
    const int*   tmask = (const int*)d_in[3];
    const float* W_ada = (const float*)d_in[4];
    const float* b_ada = (const float*)d_in[5];
    const float* W_qkv = (const float*)d_in[6];
    const float* b_qkv = (const float*)d_in[7];
    const float* W_sa  = (const float*)d_in[8];
    const float* b_sa  = (const float*)d_in[9];
    const float* W_q   = (const float*)d_in[10];
    const float* b_q   = (const float*)d_in[11];
    const float* W_kv  = (const float*)d_in[12];
    const float* b_kv  = (const float*)d_in[13];
    const float* W_ca  = (const float*)d_in[14];
    const float* b_ca  = (const float*)d_in[15];
    const float* W_fc1 = (const float*)d_in[16];
    const float* b_fc1 = (const float*)d_in[17];
    const float* W_fc2 = (const float*)d_in[18];
    const float* b_fc2 = (const float*)d_in[19];
    float* out = (float*)d_out;

    char* ws = (char*)d_ws;
    size_t off = 0;
    auto alloc = [&](size_t bytes) -> char* {
        char* p = ws + off;
        off += (bytes + 255) & ~(size_t)255;
        return p;
    };
    float* ada  = (float*)alloc((size_t)8 * 6144 * 4);
    bf16* ctxb  = (bf16*)alloc((size_t)1024 * 1024 * 2);
    bf16* WqkvT = (bf16*)alloc((size_t)3072 * 1024 * 2);
    bf16* WsaT  = (bf16*)alloc((size_t)1024 * 1024 * 2);
    bf16* WqT   = (bf16*)alloc((size_t)1024 * 1024 * 2);
    bf16* WkvT  = (bf16*)alloc((size_t)2048 * 1024 * 2);
    bf16* WcaT  = (bf16*)alloc((size_t)1024 * 1024 * 2);
    bf16* Wfc1T = (bf16*)alloc((size_t)4096 * 1024 * 2);
    bf16* Wfc2T = (bf16*)alloc((size_t)1024 * 4096 * 2);
    float* xbuf = (float*)alloc((size_t)8192 * 1024 * 4);
    bf16* hbuf  = (bf16*)alloc((size_t)8192 * 1024 * 2);
    bf16* attnb = (bf16*)alloc((size_t)8192 * 1024 * 2);
    bf16* VtgSA = (bf16*)alloc((size_t)8192 * 1024 * 2);   // [b*1024+hd][n]
    bf16* VtgCA = (bf16*)alloc((size_t)8192 * 128 * 2);    // [b*1024+hd][m]
    bf16* pool  = (bf16*)alloc((size_t)8192 * 4096 * 2);   // qkv | q+kv | gelu
    if (off > ws_size) return;

    bf16* qkvb  = pool;
    bf16* qb    = pool;
    bf16* kvb   = pool + (size_t)8192 * 1024;
    bf16* gelub = pool;

    // --- weight prep ---
    transpose_k<<<dim3(3072 / 32, 1024 / 32), 256, 0, stream>>>(W_qkv, WqkvT, 1024, 3072);
    transpose_k<<<dim3(1024 / 32, 1024 / 32), 256, 0, stream>>>(W_sa,  WsaT,  1024, 1024);
    transpose_k<<<dim3(1024 / 32, 1024 / 32), 256, 0, stream>>>(W_q,   WqT,   1024, 1024);
    transpose_k<<<dim3(2048 / 32, 1024 / 32), 256, 0, stream>>>(W_kv,  WkvT,  1024, 2048);
    transpose_k<<<dim3(1024 / 32, 1024 / 32), 256, 0, stream>>>(W_ca,  WcaT,  1024, 1024);
    transpose_k<<<dim3(4096 / 32, 1024 / 32), 256, 0, stream>>>(W_fc1, Wfc1T, 1024, 4096);
    transpose_k<<<dim3(1024 / 32, 4096 / 32), 256, 0, stream>>>(W_fc2, Wfc2T, 4096, 1024);
    cvt_bf16_k<<<1024, 256, 0, stream>>>(ctext, ctxb, 262144);

    // --- ada ---
    ada_init_k<<<192, 256, 0, stream>>>(b_ada, ada);
    ada_k<<<dim3(24, 32), 256, 0, stream>>>(cdino, W_ada, ada);

    // --- self-attention ---
    ln_mod_k<<<8192, 256, 0, stream>>>(x, ada, 0, 1024, hbuf);
    gemm_k<2><<<dim3(24, 64), 256, 0, stream>>>(hbuf, WqkvT, b_qkv, nullptr, nullptr, qkvb, 3072, 1024);
    vtrans_k<<<dim3(32, 32, 8), 256, 0, stream>>>(qkvb, 3072, 2048, 1024, VtgSA);
    attn_k<false><<<dim3(16, 16, 8), 256, 0, stream>>>(qkvb, 3072, qkvb + 1024, 3072, VtgSA,
                                                       nullptr, 1024, attnb);
    gemm_k<1><<<dim3(8, 64), 256, 0, stream>>>(attnb, WsaT, b_sa, x, xbuf, nullptr, 1024, 1024);

    // --- cross-attention ---
    ln_mod_k<<<8192, 256, 0, stream>>>(xbuf, ada, 2048, 3072, hbuf);
    gemm_k<2><<<dim3(8, 64), 256, 0, stream>>>(hbuf, WqT, b_q, nullptr, nullptr, qb, 1024, 1024);
    gemm_k<2><<<dim3(16, 8), 256, 0, stream>>>(ctxb, WkvT, b_kv, nullptr, nullptr, kvb, 2048, 1024);
    vtrans_k<<<dim3(4, 32, 8), 256, 0, stream>>>(kvb, 2048, 1024, 128, VtgCA);
    attn_k<true><<<dim3(16, 16, 8), 256, 0, stream>>>(qb, 1024, kvb, 2048, VtgCA,
                                                      tmask, 128, attnb);
    gemm_k<1><<<dim3(8, 64), 256, 0, stream>>>(attnb, WcaT, b_ca, xbuf, xbuf, nullptr, 1024, 1024);

    // --- MLP ---
    ln_mod_k<<<8192, 256, 0, stream>>>(xbuf, ada, 4096, 5120, hbuf);
    gemm_k<3><<<dim3(32, 64), 256, 0, stream>>>(hbuf, Wfc1T, b_fc1, nullptr, nullptr, gelub, 4096, 1024);
    gemm_k<1><<<dim3(8, 64), 256, 0, stream>>>(gelub, Wfc2T, b_fc2, xbuf, out, nullptr, 1024, 4096);
}

// Round 4
// 755.432 us; speedup vs baseline: 1.3488x; 1.0467x over previous
//
#include <hip/hip_runtime.h>
#include <hip/hip_bf16.h>

// Problem constants
#define B_   8
#define N_   1024
#define M_   128
#define C_   1024
#define H_   16
#define D_   64
#define MLP_ 4096

typedef __bf16 bf16;
typedef __bf16 bf16x8 __attribute__((ext_vector_type(8)));
typedef __bf16 bf16x4 __attribute__((ext_vector_type(4)));
typedef float  f32x4  __attribute__((ext_vector_type(4)));

__device__ __forceinline__ f32x4 mfma16(bf16x8 a, bf16x8 b, f32x4 c) {
    return __builtin_amdgcn_mfma_f32_16x16x32_bf16(a, b, c, 0, 0, 0);
}

// async global->LDS, 16 B per lane (LDS dest wave-uniform base + lane*16)
__device__ __forceinline__ void gload16(const bf16* g, bf16* l) {
    __builtin_amdgcn_global_load_lds(
        (const __attribute__((address_space(1))) void*)g,
        (__attribute__((address_space(3))) void*)l, 16, 0, 0);
}

// ---------------------------------------------------------------------------
// Weight transpose + fp32->bf16:  W (K x Nc) fp32  ->  Wt (Nc x K) bf16
// ---------------------------------------------------------------------------
__global__ __launch_bounds__(256) void transpose_k(const float* __restrict__ W,
                                                   bf16* __restrict__ Wt,
                                                   int K, int Nc) {
    __shared__ float tile[32][33];
    const int x  = threadIdx.x & 31;
    const int y0 = threadIdx.x >> 5;
    const size_t n0 = (size_t)blockIdx.x * 32;
    const size_t k0 = (size_t)blockIdx.y * 32;
#pragma unroll
    for (int i = 0; i < 4; i++)
        tile[y0 + i * 8][x] = W[(k0 + y0 + i * 8) * Nc + n0 + x];
    __syncthreads();
#pragma unroll
    for (int i = 0; i < 4; i++)
        Wt[(n0 + y0 + i * 8) * K + k0 + x] = (bf16)tile[x][y0 + i * 8];
}

// bf16 V transpose: in rows (b*Mk + m), cols coff+hd -> outT[(b*1024+hd)*Mk + m]
__global__ __launch_bounds__(256) void vtrans_k(const bf16* __restrict__ in, int instride,
                                                int coff, int Mk, bf16* __restrict__ outT) {
    __shared__ bf16 t[32][33];
    const int tx = threadIdx.x & 31;
    const int ty0 = threadIdx.x >> 5;
    const int m0  = blockIdx.x * 32;
    const int hd0 = blockIdx.y * 32;
    const int b   = blockIdx.z;
#pragma unroll
    for (int i = 0; i < 4; i++)
        t[ty0 + i * 8][tx] = in[((size_t)(b * Mk + m0 + ty0 + i * 8)) * instride + coff + hd0 + tx];
    __syncthreads();
#pragma unroll
    for (int i = 0; i < 4; i++)
        outT[((size_t)(b * 1024 + hd0 + ty0 + i * 8)) * Mk + m0 + tx] = t[tx][ty0 + i * 8];
}

// fp32 -> bf16 elementwise (n4 = count/4)
__global__ __launch_bounds__(256) void cvt_bf16_k(const float* __restrict__ in,
                                                  bf16* __restrict__ out, int n4) {
    int i = blockIdx.x * 256 + threadIdx.x;
    if (i < n4) {
        float4 v = ((const float4*)in)[i];
        bf16x4 o;
        o[0] = (bf16)v.x; o[1] = (bf16)v.y; o[2] = (bf16)v.z; o[3] = (bf16)v.w;
        ((bf16x4*)out)[i] = o;
    }
}

// ---------------------------------------------------------------------------
// ada = silu(c_dino) @ W_ada + b_ada   (8 x 6144) fp32, split-K with atomics.
// ---------------------------------------------------------------------------
__global__ __launch_bounds__(256) void ada_init_k(const float* __restrict__ bias,
                                                  float* __restrict__ ada) {
    int i = blockIdx.x * 256 + threadIdx.x;
    ada[i] = bias[i % 6144];
}

__global__ __launch_bounds__(256) void ada_k(const float* __restrict__ cdino,
                                             const float* __restrict__ W,
                                             float* __restrict__ ada) {
    __shared__ float sc[8][32];
    const int tid = threadIdx.x;
    const int k0  = blockIdx.y * 32;
    {
        float c = cdino[(tid >> 5) * 1024 + k0 + (tid & 31)];
        sc[tid >> 5][tid & 31] = c / (1.f + __expf(-c));
    }
    __syncthreads();
    const int col = blockIdx.x * 256 + tid;
    float acc[8];
#pragma unroll
    for (int b = 0; b < 8; b++) acc[b] = 0.f;
    for (int kk = 0; kk < 32; kk++) {
        float w = W[(size_t)(k0 + kk) * 6144 + col];
#pragma unroll
        for (int b = 0; b < 8; b++) acc[b] += sc[b][kk] * w;
    }
#pragma unroll
    for (int b = 0; b < 8; b++) atomicAdd(&ada[(size_t)b * 6144 + col], acc[b]);
}

// ---------------------------------------------------------------------------
// h = modulate(LN(x), shift, scale)  -> bf16
// ---------------------------------------------------------------------------
__global__ __launch_bounds__(256) void ln_mod_k(const float* __restrict__ X,
                                                const float* __restrict__ ada,
                                                int shoff, int scoff,
                                                bf16* __restrict__ Hout) {
    const int row = blockIdx.x;
    const int b   = row >> 10;
    const int tid = threadIdx.x;
    const float4 v = ((const float4*)(X + (size_t)row * C_))[tid];
    float s  = v.x + v.y + v.z + v.w;
    float sq = v.x * v.x + v.y * v.y + v.z * v.z + v.w * v.w;
#pragma unroll
    for (int off = 32; off; off >>= 1) {
        s  += __shfl_xor(s,  off);
        sq += __shfl_xor(sq, off);
    }
    __shared__ float rs_[4], rq_[4];
    if ((tid & 63) == 0) { rs_[tid >> 6] = s; rq_[tid >> 6] = sq; }
    __syncthreads();
    s  = rs_[0] + rs_[1] + rs_[2] + rs_[3];
    sq = rq_[0] + rq_[1] + rq_[2] + rq_[3];
    const float mu   = s * (1.f / 1024.f);
    const float var  = sq * (1.f / 1024.f) - mu * mu;
    const float rstd = rsqrtf(var + 1e-6f);
    const float4 scv = ((const float4*)(ada + (size_t)b * 6144 + scoff))[tid];
    const float4 shv = ((const float4*)(ada + (size_t)b * 6144 + shoff))[tid];
    bf16x4 o;
    o[0] = (bf16)(((v.x - mu) * rstd) * (1.f + scv.x) + shv.x);
    o[1] = (bf16)(((v.y - mu) * rstd) * (1.f + scv.y) + shv.y);
    o[2] = (bf16)(((v.z - mu) * rstd) * (1.f + scv.z) + shv.z);
    o[3] = (bf16)(((v.w - mu) * rstd) * (1.f + scv.w) + shv.w);
    *(bf16x4*)(Hout + (size_t)row * C_ + tid * 4) = o;
}

// ---------------------------------------------------------------------------
// Generic bf16 MFMA GEMM (m97 structure + LDS XOR swizzle + XCD-local grid).
// 1-D grid of GX*GY blocks. xcd = lid&7; within an XCD, bn iterates fastest
// so all blocks sharing an A-row-block (bm) live on one XCD, adjacent in time.
// LDS: 16B chunk at (row, physical seg p) holds logical seg p ^ ((row>>1)&3)
// -> read phases hit each bank-group exactly twice (2-way = free).
// MODE 1: fp32 out = v + resid    MODE 2: bf16 out = v    MODE 3: bf16 gelu(v)
// ---------------------------------------------------------------------------
template <int MODE>
__global__ __launch_bounds__(256) void gemm_k(const bf16* __restrict__ A,
                                              const bf16* __restrict__ Bt,
                                              const float* __restrict__ bias,
                                              const float* resid,
                                              float* outF, bf16* outB,
                                              int Ncols, int K, int GX) {
    __shared__ __attribute__((aligned(16))) bf16 As[128][32];
    __shared__ __attribute__((aligned(16))) bf16 Bs[128][32];
    const int tid  = threadIdx.x;
    const int lane = tid & 63, wave = tid >> 6;
    const int lrow = lane & 15, quad = lane >> 4;
    const int wm = wave >> 1, wn = wave & 1;

    // XCD-locality block swizzle
    const unsigned lid = blockIdx.x;
    const unsigned xcd = lid & 7, s = lid >> 3;
    const unsigned bnb = s % GX, bmb = (s / GX) * 8 + xcd;
    const size_t bm = (size_t)bmb * 128;
    const size_t bn = (size_t)bnb * 128;

    // staging: thread tid owns physical chunk tid (rows 0-63) and 256+tid;
    // physical (prow, pseg) must hold global k-seg pseg ^ ((prow>>1)&3)
    const int prow = tid >> 2, pseg = tid & 3;
    const int gseg = pseg ^ ((prow >> 1) & 3);
    const bf16* gA0 = A  + (bm + prow) * (size_t)K + gseg * 8;
    const bf16* gA1 = gA0 + (size_t)64 * K;
    const bf16* gB0 = Bt + (bn + prow) * (size_t)K + gseg * 8;
    const bf16* gB1 = gB0 + (size_t)64 * K;
    bf16* lA0 = &As[0][0] + wave * 512;
    bf16* lA1 = lA0 + 2048;
    bf16* lB0 = &Bs[0][0] + wave * 512;
    bf16* lB1 = lB0 + 2048;

    // read-side swizzled chunk offset (row base multiple of 16 -> use lrow)
    const int xoff = (quad ^ ((lrow >> 1) & 3)) * 8;

    f32x4 acc[4][4];
#pragma unroll
    for (int i = 0; i < 4; i++)
#pragma unroll
        for (int j = 0; j < 4; j++) acc[i][j] = (f32x4){0.f, 0.f, 0.f, 0.f};

    for (int ko = 0; ko < K; ko += 32) {
        gload16(gA0 + ko, lA0);
        gload16(gA1 + ko, lA1);
        gload16(gB0 + ko, lB0);
        gload16(gB1 + ko, lB1);
        __syncthreads();
        bf16x8 af[4], bfr[4];
#pragma unroll
        for (int mi = 0; mi < 4; mi++)
            af[mi] = *(const bf16x8*)&As[wm * 64 + mi * 16 + lrow][xoff];
#pragma unroll
        for (int ni = 0; ni < 4; ni++)
            bfr[ni] = *(const bf16x8*)&Bs[wn * 64 + ni * 16 + lrow][xoff];
#pragma unroll
        for (int mi = 0; mi < 4; mi++)
#pragma unroll
            for (int ni = 0; ni < 4; ni++)
                acc[mi][ni] = mfma16(af[mi], bfr[ni], acc[mi][ni]);
        __syncthreads();
    }

#pragma unroll
    for (int mi = 0; mi < 4; mi++) {
#pragma unroll
        for (int ni = 0; ni < 4; ni++) {
            const size_t gcol = bn + wn * 64 + ni * 16 + lrow;
            const float bv = bias[gcol];
#pragma unroll
            for (int r = 0; r < 4; r++) {
                const size_t grow = bm + wm * 64 + mi * 16 + quad * 4 + r;
                const size_t idx  = grow * Ncols + gcol;
                float v = acc[mi][ni][r] + bv;
                if (MODE == 1) {
                    outF[idx] = v + resid[idx];
                } else if (MODE == 2) {
                    outB[idx] = (bf16)v;
                } else {
                    float z = 1.59576912f * (v + 0.044715f * v * v * v);
                    outB[idx] = (bf16)(v / (1.f + __expf(-z)));
                }
            }
        }
    }
}

// ---------------------------------------------------------------------------
// Flash attention, S^T formulation. D=64, 64-key chunks. (unchanged R3)
// ---------------------------------------------------------------------------
template <bool MASKED>
__global__ __launch_bounds__(256) void attn_k(const bf16* __restrict__ Qp, int qstride,
                                              const bf16* __restrict__ Kp, int kstride,
                                              const bf16* __restrict__ Vtg,
                                              const int* __restrict__ mask, int Mk,
                                              bf16* __restrict__ O) {
    __shared__ __attribute__((aligned(16))) bf16 Kt[64][88];      // [key][d]
    __shared__ __attribute__((aligned(16))) bf16 Vt[64][88];      // [d][key]
    __shared__ __attribute__((aligned(16))) bf16 Pt[4][16][88];   // [wave][q][key]
    __shared__ float madd[64];

    const int b = blockIdx.z, h = blockIdx.y;
    const int tid  = threadIdx.x;
    const int lane = tid & 63, wave = tid >> 6;
    const int lrow = lane & 15, quad = lane >> 4;
    const int q0 = blockIdx.x * 64 + wave * 16;

    const bf16* qp = Qp + ((size_t)(b * N_ + q0 + lrow)) * qstride + h * 64 + quad * 8;
    const bf16x8 bq0 = *(const bf16x8*)(qp);
    const bf16x8 bq1 = *(const bf16x8*)(qp + 32);

    f32x4 acc[4];
#pragma unroll
    for (int t = 0; t < 4; t++) acc[t] = (f32x4){0.f, 0.f, 0.f, 0.f};
    float mrun = -3e38f, lrun = 0.f;

    const int srow = tid >> 2;
    const int sseg = (tid & 3) * 16;

    const bf16* kbase = Kp + ((size_t)b * Mk + srow) * kstride + h * 64 + sseg;
    const bf16* vbase = Vtg + ((size_t)(b * 1024 + h * 64 + srow)) * Mk + sseg;

    for (int kc = 0; kc < Mk; kc += 64) {
        __syncthreads();
        const bf16* kp = kbase + (size_t)kc * kstride;
        bf16x8 k0 = *(const bf16x8*)kp;
        bf16x8 k1 = *(const bf16x8*)(kp + 8);
        *(bf16x8*)&Kt[srow][sseg]     = k0;
        *(bf16x8*)&Kt[srow][sseg + 8] = k1;
        const bf16* vp = vbase + kc;
        bf16x8 v0 = *(const bf16x8*)vp;
        bf16x8 v1 = *(const bf16x8*)(vp + 8);
        *(bf16x8*)&Vt[srow][sseg]     = v0;
        *(bf16x8*)&Vt[srow][sseg + 8] = v1;
        if (MASKED && tid < 64)
            madd[tid] = (mask[b * Mk + kc + tid] == 0) ? -1e30f : 0.f;
        __syncthreads();

        float sv[4][4];
#pragma unroll
        for (int t = 0; t < 4; t++) {
            f32x4 s = (f32x4){0.f, 0.f, 0.f, 0.f};
            bf16x8 ak0 = *(const bf16x8*)&Kt[t * 16 + lrow][quad * 8];
            s = mfma16(ak0, bq0, s);
            bf16x8 ak1 = *(const bf16x8*)&Kt[t * 16 + lrow][32 + quad * 8];
            s = mfma16(ak1, bq1, s);
#pragma unroll
            for (int r = 0; r < 4; r++) {
                float ma = MASKED ? madd[t * 16 + quad * 4 + r] : 0.f;
                sv[t][r] = s[r] * 0.125f + ma;
            }
        }

        float vmax = sv[0][0];
#pragma unroll
        for (int t = 0; t < 4; t++)
#pragma unroll
            for (int r = 0; r < 4; r++) vmax = fmaxf(vmax, sv[t][r]);
        vmax = fmaxf(vmax, __shfl_xor(vmax, 16));
        vmax = fmaxf(vmax, __shfl_xor(vmax, 32));
        const float mnew  = fmaxf(mrun, vmax);
        const float alpha = __expf(mrun - mnew);
        mrun = mnew;
        float rsum = 0.f;
#pragma unroll
        for (int t = 0; t < 4; t++) {
            bf16x4 p4;
#pragma unroll
            for (int r = 0; r < 4; r++) {
                float p = __expf(sv[t][r] - mnew);
                rsum += p;
                p4[r] = (bf16)p;
            }
            *(bf16x4*)&Pt[wave][lrow][t * 16 + quad * 4] = p4;
        }
        rsum += __shfl_xor(rsum, 16);
        rsum += __shfl_xor(rsum, 32);
        lrun = lrun * alpha + rsum;

        float alpha4[4];
#pragma unroll
        for (int r = 0; r < 4; r++) alpha4[r] = __shfl(alpha, quad * 4 + r);
#pragma unroll
        for (int t = 0; t < 4; t++)
#pragma unroll
            for (int r = 0; r < 4; r++) acc[t][r] *= alpha4[r];

        __syncthreads();
        const bf16x8 ap0 = *(const bf16x8*)&Pt[wave][lrow][quad * 8];
        const bf16x8 ap1 = *(const bf16x8*)&Pt[wave][lrow][32 + quad * 8];

#pragma unroll
        for (int t = 0; t < 4; t++) {
            bf16x8 bv0 = *(const bf16x8*)&Vt[t * 16 + lrow][quad * 8];
            acc[t] = mfma16(ap0, bv0, acc[t]);
            bf16x8 bv1 = *(const bf16x8*)&Vt[t * 16 + lrow][32 + quad * 8];
            acc[t] = mfma16(ap1, bv1, acc[t]);
        }
    }

    float linv = 1.f / lrun;
    float linv4[4];
#pragma unroll
    for (int r = 0; r < 4; r++) linv4[r] = __shfl(linv, quad * 4 + r);
#pragma unroll
    for (int r = 0; r < 4; r++) {
        const size_t grow = (size_t)(b * N_ + q0 + quad * 4 + r);
#pragma unroll
        for (int t = 0; t < 4; t++)
            O[grow * C_ + h * 64 + t * 16 + lrow] = (bf16)(acc[t][r] * linv4[r]);
    }
}

// ---------------------------------------------------------------------------
extern "C" void kernel_launch(void* const* d_in, const int* in_sizes, int n_in,
                              void* d_out, int out_size, void* d_ws, size_t ws_size,
                              hipStream_t stream) {
    const float* x     = (const float*)d_in[0];
    const float* cdino = (const float*)d_in[1];
    const float* ctext = (const float*)d_in[2];
    const int*   tmask = (const int*)d_in[3];
    const float* W_ada = (const float*)d_in[4];
    const float* b_ada = (const float*)d_in[5];
    const float* W_qkv = (const float*)d_in[6];
    const float* b_qkv = (const float*)d_in[7];
    const float* W_sa  = (const float*)d_in[8];
    const float* b_sa  = (const float*)d_in[9];
    const float* W_q   = (const float*)d_in[10];
    const float* b_q   = (const float*)d_in[11];
    const float* W_kv  = (const float*)d_in[12];
    const float* b_kv  = (const float*)d_in[13];
    const float* W_ca  = (const float*)d_in[14];
    const float* b_ca  = (const float*)d_in[15];
    const float* W_fc1 = (const float*)d_in[16];
    const float* b_fc1 = (const float*)d_in[17];
    const float* W_fc2 = (const float*)d_in[18];
    const float* b_fc2 = (const float*)d_in[19];
    float* out = (float*)d_out;

    char* ws = (char*)d_ws;
    size_t off = 0;
    auto alloc = [&](size_t bytes) -> char* {
        char* p = ws + off;
        off += (bytes + 255) & ~(size_t)255;
        return p;
    };
    float* ada  = (float*)alloc((size_t)8 * 6144 * 4);
    bf16* ctxb  = (bf16*)alloc((size_t)1024 * 1024 * 2);
    bf16* WqkvT = (bf16*)alloc((size_t)3072 * 1024 * 2);
    bf16* WsaT  = (bf16*)alloc((size_t)1024 * 1024 * 2);
    bf16* WqT   = (bf16*)alloc((size_t)1024 * 1024 * 2);
    bf16* WkvT  = (bf16*)alloc((size_t)2048 * 1024 * 2);
    bf16* WcaT  = (bf16*)alloc((size_t)1024 * 1024 * 2);
    bf16* Wfc1T = (bf16*)alloc((size_t)4096 * 1024 * 2);
    bf16* Wfc2T = (bf16*)alloc((size_t)1024 * 4096 * 2);
    float* xbuf = (float*)alloc((size_t)8192 * 1024 * 4);
    bf16* hbuf  = (bf16*)alloc((size_t)8192 * 1024 * 2);
    bf16* attnb = (bf16*)alloc((size_t)8192 * 1024 * 2);
    bf16* VtgSA = (bf16*)alloc((size_t)8192 * 1024 * 2);
    bf16* VtgCA = (bf16*)alloc((size_t)8192 * 128 * 2);
    bf16* pool  = (bf16*)alloc((size_t)8192 * 4096 * 2);
    if (off > ws_size) return;

    bf16* qkvb  = pool;
    bf16* qb    = pool;
    bf16* kvb   = pool + (size_t)8192 * 1024;
    bf16* gelub = pool;

    // --- weight prep ---
    transpose_k<<<dim3(3072 / 32, 1024 / 32), 256, 0, stream>>>(W_qkv, WqkvT, 1024, 3072);
    transpose_k<<<dim3(1024 / 32, 1024 / 32), 256, 0, stream>>>(W_sa,  WsaT,  1024, 1024);
    transpose_k<<<dim3(1024 / 32, 1024 / 32), 256, 0, stream>>>(W_q,   WqT,   1024, 1024);
    transpose_k<<<dim3(2048 / 32, 1024 / 32), 256, 0, stream>>>(W_kv,  WkvT,  1024, 2048);
    transpose_k<<<dim3(1024 / 32, 1024 / 32), 256, 0, stream>>>(W_ca,  WcaT,  1024, 1024);
    transpose_k<<<dim3(4096 / 32, 1024 / 32), 256, 0, stream>>>(W_fc1, Wfc1T, 1024, 4096);
    transpose_k<<<dim3(1024 / 32, 4096 / 32), 256, 0, stream>>>(W_fc2, Wfc2T, 4096, 1024);
    cvt_bf16_k<<<1024, 256, 0, stream>>>(ctext, ctxb, 262144);

    // --- ada ---
    ada_init_k<<<192, 256, 0, stream>>>(b_ada, ada);
    ada_k<<<dim3(24, 32), 256, 0, stream>>>(cdino, W_ada, ada);

    // --- self-attention ---
    ln_mod_k<<<8192, 256, 0, stream>>>(x, ada, 0, 1024, hbuf);
    gemm_k<2><<<24 * 64, 256, 0, stream>>>(hbuf, WqkvT, b_qkv, nullptr, nullptr, qkvb, 3072, 1024, 24);
    vtrans_k<<<dim3(32, 32, 8), 256, 0, stream>>>(qkvb, 3072, 2048, 1024, VtgSA);
    attn_k<false><<<dim3(16, 16, 8), 256, 0, stream>>>(qkvb, 3072, qkvb + 1024, 3072, VtgSA,
                                                       nullptr, 1024, attnb);
    gemm_k<1><<<8 * 64, 256, 0, stream>>>(attnb, WsaT, b_sa, x, xbuf, nullptr, 1024, 1024, 8);

    // --- cross-attention ---
    ln_mod_k<<<8192, 256, 0, stream>>>(xbuf, ada, 2048, 3072, hbuf);
    gemm_k<2><<<8 * 64, 256, 0, stream>>>(hbuf, WqT, b_q, nullptr, nullptr, qb, 1024, 1024, 8);
    gemm_k<2><<<16 * 8, 256, 0, stream>>>(ctxb, WkvT, b_kv, nullptr, nullptr, kvb, 2048, 1024, 16);
    vtrans_k<<<dim3(4, 32, 8), 256, 0, stream>>>(kvb, 2048, 1024, 128, VtgCA);
    attn_k<true><<<dim3(16, 16, 8), 256, 0, stream>>>(qb, 1024, kvb, 2048, VtgCA,
                                                      tmask, 128, attnb);
    gemm_k<1><<<8 * 64, 256, 0, stream>>>(attnb, WcaT, b_ca, xbuf, xbuf, nullptr, 1024, 1024, 8);

    // --- MLP ---
    ln_mod_k<<<8192, 256, 0, stream>>>(xbuf, ada, 4096, 5120, hbuf);
    gemm_k<3><<<32 * 64, 256, 0, stream>>>(hbuf, Wfc1T, b_fc1, nullptr, nullptr, gelub, 4096, 1024, 32);
    gemm_k<1><<<8 * 64, 256, 0, stream>>>(gelub, Wfc2T, b_fc2, xbuf, out, nullptr, 1024, 4096, 8);
}

// Round 5
// 743.493 us; speedup vs baseline: 1.3705x; 1.0161x over previous
//
#include <hip/hip_runtime.h>
#include <hip/hip_bf16.h>

// Problem constants
#define B_   8
#define N_   1024
#define M_   128
#define C_   1024
#define H_   16
#define D_   64
#define MLP_ 4096

typedef __bf16 bf16;
typedef __bf16 bf16x8 __attribute__((ext_vector_type(8)));
typedef __bf16 bf16x4 __attribute__((ext_vector_type(4)));
typedef float  f32x4  __attribute__((ext_vector_type(4)));

__device__ __forceinline__ f32x4 mfma16(bf16x8 a, bf16x8 b, f32x4 c) {
    return __builtin_amdgcn_mfma_f32_16x16x32_bf16(a, b, c, 0, 0, 0);
}

// async global->LDS, 16 B per lane (LDS dest wave-uniform base + lane*16)
__device__ __forceinline__ void gload16(const bf16* g, bf16* l) {
    __builtin_amdgcn_global_load_lds(
        (const __attribute__((address_space(1))) void*)g,
        (__attribute__((address_space(3))) void*)l, 16, 0, 0);
}

// ---------------------------------------------------------------------------
// Weight transpose + fp32->bf16:  W (K x Nc) fp32  ->  Wt (Nc x K) bf16
// ---------------------------------------------------------------------------
__global__ __launch_bounds__(256) void transpose_k(const float* __restrict__ W,
                                                   bf16* __restrict__ Wt,
                                                   int K, int Nc) {
    __shared__ float tile[32][33];
    const int x  = threadIdx.x & 31;
    const int y0 = threadIdx.x >> 5;
    const size_t n0 = (size_t)blockIdx.x * 32;
    const size_t k0 = (size_t)blockIdx.y * 32;
#pragma unroll
    for (int i = 0; i < 4; i++)
        tile[y0 + i * 8][x] = W[(k0 + y0 + i * 8) * Nc + n0 + x];
    __syncthreads();
#pragma unroll
    for (int i = 0; i < 4; i++)
        Wt[(n0 + y0 + i * 8) * K + k0 + x] = (bf16)tile[x][y0 + i * 8];
}

// bf16 V transpose: in rows (b*Mk + m), cols coff+hd -> outT[(b*1024+hd)*Mk + m]
__global__ __launch_bounds__(256) void vtrans_k(const bf16* __restrict__ in, int instride,
                                                int coff, int Mk, bf16* __restrict__ outT) {
    __shared__ bf16 t[32][33];
    const int tx = threadIdx.x & 31;
    const int ty0 = threadIdx.x >> 5;
    const int m0  = blockIdx.x * 32;
    const int hd0 = blockIdx.y * 32;
    const int b   = blockIdx.z;
#pragma unroll
    for (int i = 0; i < 4; i++)
        t[ty0 + i * 8][tx] = in[((size_t)(b * Mk + m0 + ty0 + i * 8)) * instride + coff + hd0 + tx];
    __syncthreads();
#pragma unroll
    for (int i = 0; i < 4; i++)
        outT[((size_t)(b * 1024 + hd0 + ty0 + i * 8)) * Mk + m0 + tx] = t[tx][ty0 + i * 8];
}

// fp32 -> bf16 elementwise (n4 = count/4)
__global__ __launch_bounds__(256) void cvt_bf16_k(const float* __restrict__ in,
                                                  bf16* __restrict__ out, int n4) {
    int i = blockIdx.x * 256 + threadIdx.x;
    if (i < n4) {
        float4 v = ((const float4*)in)[i];
        bf16x4 o;
        o[0] = (bf16)v.x; o[1] = (bf16)v.y; o[2] = (bf16)v.z; o[3] = (bf16)v.w;
        ((bf16x4*)out)[i] = o;
    }
}

// ---------------------------------------------------------------------------
// ada = silu(c_dino) @ W_ada + b_ada   (8 x 6144) fp32, split-K with atomics.
// ---------------------------------------------------------------------------
__global__ __launch_bounds__(256) void ada_init_k(const float* __restrict__ bias,
                                                  float* __restrict__ ada) {
    int i = blockIdx.x * 256 + threadIdx.x;
    ada[i] = bias[i % 6144];
}

__global__ __launch_bounds__(256) void ada_k(const float* __restrict__ cdino,
                                             const float* __restrict__ W,
                                             float* __restrict__ ada) {
    __shared__ float sc[8][32];
    const int tid = threadIdx.x;
    const int k0  = blockIdx.y * 32;
    {
        float c = cdino[(tid >> 5) * 1024 + k0 + (tid & 31)];
        sc[tid >> 5][tid & 31] = c / (1.f + __expf(-c));
    }
    __syncthreads();
    const int col = blockIdx.x * 256 + tid;
    float acc[8];
#pragma unroll
    for (int b = 0; b < 8; b++) acc[b] = 0.f;
    for (int kk = 0; kk < 32; kk++) {
        float w = W[(size_t)(k0 + kk) * 6144 + col];
#pragma unroll
        for (int b = 0; b < 8; b++) acc[b] += sc[b][kk] * w;
    }
#pragma unroll
    for (int b = 0; b < 8; b++) atomicAdd(&ada[(size_t)b * 6144 + col], acc[b]);
}

// ---------------------------------------------------------------------------
// h = modulate(LN(x), shift, scale)  -> bf16
// ---------------------------------------------------------------------------
__global__ __launch_bounds__(256) void ln_mod_k(const float* __restrict__ X,
                                                const float* __restrict__ ada,
                                                int shoff, int scoff,
                                                bf16* __restrict__ Hout) {
    const int row = blockIdx.x;
    const int b   = row >> 10;
    const int tid = threadIdx.x;
    const float4 v = ((const float4*)(X + (size_t)row * C_))[tid];
    float s  = v.x + v.y + v.z + v.w;
    float sq = v.x * v.x + v.y * v.y + v.z * v.z + v.w * v.w;
#pragma unroll
    for (int off = 32; off; off >>= 1) {
        s  += __shfl_xor(s,  off);
        sq += __shfl_xor(sq, off);
    }
    __shared__ float rs_[4], rq_[4];
    if ((tid & 63) == 0) { rs_[tid >> 6] = s; rq_[tid >> 6] = sq; }
    __syncthreads();
    s  = rs_[0] + rs_[1] + rs_[2] + rs_[3];
    sq = rq_[0] + rq_[1] + rq_[2] + rq_[3];
    const float mu   = s * (1.f / 1024.f);
    const float var  = sq * (1.f / 1024.f) - mu * mu;
    const float rstd = rsqrtf(var + 1e-6f);
    const float4 scv = ((const float4*)(ada + (size_t)b * 6144 + scoff))[tid];
    const float4 shv = ((const float4*)(ada + (size_t)b * 6144 + shoff))[tid];
    bf16x4 o;
    o[0] = (bf16)(((v.x - mu) * rstd) * (1.f + scv.x) + shv.x);
    o[1] = (bf16)(((v.y - mu) * rstd) * (1.f + scv.y) + shv.y);
    o[2] = (bf16)(((v.z - mu) * rstd) * (1.f + scv.z) + shv.z);
    o[3] = (bf16)(((v.w - mu) * rstd) * (1.f + scv.w) + shv.w);
    *(bf16x4*)(Hout + (size_t)row * C_ + tid * 4) = o;
}

// ---------------------------------------------------------------------------
// Generic bf16 MFMA GEMM (m97 structure + LDS XOR swizzle + XCD-local grid
// + optional in-block split-K).
// KS=1: 256 threads. KS=2: 512 threads, two 4-wave groups each compute half
// of K into identical 128x128 tiles (private LDS staging), then group 1's
// accumulators fold into group 0 via LDS (reusing As region) and group 0
// runs the epilogue. Doubles resident waves for small grids; no extra HBM.
// MODE 1: fp32 out = v + resid    MODE 2: bf16 out = v    MODE 3: bf16 gelu(v)
// ---------------------------------------------------------------------------
template <int MODE, int KS>
__global__ __launch_bounds__(256 * KS) void gemm_k(const bf16* __restrict__ A,
                                                   const bf16* __restrict__ Bt,
                                                   const float* __restrict__ bias,
                                                   const float* resid,
                                                   float* outF, bf16* outB,
                                                   int Ncols, int K, int GX) {
    __shared__ __attribute__((aligned(16))) bf16 As[KS][128][32];
    __shared__ __attribute__((aligned(16))) bf16 Bs[KS][128][32];
    const int tid  = threadIdx.x & 255;     // within-group thread id
    const int grp  = threadIdx.x >> 8;      // k-group (0..KS-1)
    const int lane = tid & 63, wave = tid >> 6;
    const int lrow = lane & 15, quad = lane >> 4;
    const int wm = wave >> 1, wn = wave & 1;

    // XCD-locality block swizzle
    const unsigned lid = blockIdx.x;
    const unsigned xcd = lid & 7, s = lid >> 3;
    const unsigned bnb = s % GX, bmb = (s / GX) * 8 + xcd;
    const size_t bm = (size_t)bmb * 128;
    const size_t bn = (size_t)bnb * 128;

    const int Kh = K / KS;                  // per-group K extent
    // staging: physical (prow, pseg) holds global k-seg pseg ^ ((prow>>1)&3)
    const int prow = tid >> 2, pseg = tid & 3;
    const int gseg = pseg ^ ((prow >> 1) & 3);
    const bf16* gA0 = A  + (bm + prow) * (size_t)K + grp * Kh + gseg * 8;
    const bf16* gA1 = gA0 + (size_t)64 * K;
    const bf16* gB0 = Bt + (bn + prow) * (size_t)K + grp * Kh + gseg * 8;
    const bf16* gB1 = gB0 + (size_t)64 * K;
    bf16* lA0 = &As[grp][0][0] + wave * 512;
    bf16* lA1 = lA0 + 2048;
    bf16* lB0 = &Bs[grp][0][0] + wave * 512;
    bf16* lB1 = lB0 + 2048;

    // read-side swizzled chunk offset
    const int xoff = (quad ^ ((lrow >> 1) & 3)) * 8;

    f32x4 acc[4][4];
#pragma unroll
    for (int i = 0; i < 4; i++)
#pragma unroll
        for (int j = 0; j < 4; j++) acc[i][j] = (f32x4){0.f, 0.f, 0.f, 0.f};

    for (int ko = 0; ko < Kh; ko += 32) {
        gload16(gA0 + ko, lA0);
        gload16(gA1 + ko, lA1);
        gload16(gB0 + ko, lB0);
        gload16(gB1 + ko, lB1);
        __syncthreads();
        bf16x8 af[4], bfr[4];
#pragma unroll
        for (int mi = 0; mi < 4; mi++)
            af[mi] = *(const bf16x8*)&As[grp][wm * 64 + mi * 16 + lrow][xoff];
#pragma unroll
        for (int ni = 0; ni < 4; ni++)
            bfr[ni] = *(const bf16x8*)&Bs[grp][wn * 64 + ni * 16 + lrow][xoff];
#pragma unroll
        for (int mi = 0; mi < 4; mi++)
#pragma unroll
            for (int ni = 0; ni < 4; ni++)
                acc[mi][ni] = mfma16(af[mi], bfr[ni], acc[mi][ni]);
        __syncthreads();
    }

    // in-block split-K reduction: group 1 -> LDS (As region) -> group 0.
    if constexpr (KS == 2) {
        f32x4* red = (f32x4*)&As[0][0][0];   // 16 KB = 1024 f32x4
#pragma unroll
        for (int rnd = 0; rnd < 4; rnd++) {
            __syncthreads();
            if (grp == 1) {
#pragma unroll
                for (int c = 0; c < 4; c++) {
                    const int idx = rnd * 4 + c;
                    red[c * 256 + tid] = acc[idx >> 2][idx & 3];
                }
            }
            __syncthreads();
            if (grp == 0) {
#pragma unroll
                for (int c = 0; c < 4; c++) {
                    const int idx = rnd * 4 + c;
                    acc[idx >> 2][idx & 3] += red[c * 256 + tid];
                }
            }
        }
    }

    if (grp == 0) {
#pragma unroll
        for (int mi = 0; mi < 4; mi++) {
#pragma unroll
            for (int ni = 0; ni < 4; ni++) {
                const size_t gcol = bn + wn * 64 + ni * 16 + lrow;
                const float bv = bias[gcol];
#pragma unroll
                for (int r = 0; r < 4; r++) {
                    const size_t grow = bm + wm * 64 + mi * 16 + quad * 4 + r;
                    const size_t idx  = grow * Ncols + gcol;
                    float v = acc[mi][ni][r] + bv;
                    if (MODE == 1) {
                        outF[idx] = v + resid[idx];
                    } else if (MODE == 2) {
                        outB[idx] = (bf16)v;
                    } else {
                        float z = 1.59576912f * (v + 0.044715f * v * v * v);
                        outB[idx] = (bf16)(v / (1.f + __expf(-z)));
                    }
                }
            }
        }
    }
}

// ---------------------------------------------------------------------------
// Flash attention, S^T formulation. D=64, 64-key chunks. (unchanged)
// ---------------------------------------------------------------------------
template <bool MASKED>
__global__ __launch_bounds__(256) void attn_k(const bf16* __restrict__ Qp, int qstride,
                                              const bf16* __restrict__ Kp, int kstride,
                                              const bf16* __restrict__ Vtg,
                                              const int* __restrict__ mask, int Mk,
                                              bf16* __restrict__ O) {
    __shared__ __attribute__((aligned(16))) bf16 Kt[64][88];      // [key][d]
    __shared__ __attribute__((aligned(16))) bf16 Vt[64][88];      // [d][key]
    __shared__ __attribute__((aligned(16))) bf16 Pt[4][16][88];   // [wave][q][key]
    __shared__ float madd[64];

    const int b = blockIdx.z, h = blockIdx.y;
    const int tid  = threadIdx.x;
    const int lane = tid & 63, wave = tid >> 6;
    const int lrow = lane & 15, quad = lane >> 4;
    const int q0 = blockIdx.x * 64 + wave * 16;

    const bf16* qp = Qp + ((size_t)(b * N_ + q0 + lrow)) * qstride + h * 64 + quad * 8;
    const bf16x8 bq0 = *(const bf16x8*)(qp);
    const bf16x8 bq1 = *(const bf16x8*)(qp + 32);

    f32x4 acc[4];
#pragma unroll
    for (int t = 0; t < 4; t++) acc[t] = (f32x4){0.f, 0.f, 0.f, 0.f};
    float mrun = -3e38f, lrun = 0.f;

    const int srow = tid >> 2;
    const int sseg = (tid & 3) * 16;

    const bf16* kbase = Kp + ((size_t)b * Mk + srow) * kstride + h * 64 + sseg;
    const bf16* vbase = Vtg + ((size_t)(b * 1024 + h * 64 + srow)) * Mk + sseg;

    for (int kc = 0; kc < Mk; kc += 64) {
        __syncthreads();
        const bf16* kp = kbase + (size_t)kc * kstride;
        bf16x8 k0 = *(const bf16x8*)kp;
        bf16x8 k1 = *(const bf16x8*)(kp + 8);
        *(bf16x8*)&Kt[srow][sseg]     = k0;
        *(bf16x8*)&Kt[srow][sseg + 8] = k1;
        const bf16* vp = vbase + kc;
        bf16x8 v0 = *(const bf16x8*)vp;
        bf16x8 v1 = *(const bf16x8*)(vp + 8);
        *(bf16x8*)&Vt[srow][sseg]     = v0;
        *(bf16x8*)&Vt[srow][sseg + 8] = v1;
        if (MASKED && tid < 64)
            madd[tid] = (mask[b * Mk + kc + tid] == 0) ? -1e30f : 0.f;
        __syncthreads();

        float sv[4][4];
#pragma unroll
        for (int t = 0; t < 4; t++) {
            f32x4 s = (f32x4){0.f, 0.f, 0.f, 0.f};
            bf16x8 ak0 = *(const bf16x8*)&Kt[t * 16 + lrow][quad * 8];
            s = mfma16(ak0, bq0, s);
            bf16x8 ak1 = *(const bf16x8*)&Kt[t * 16 + lrow][32 + quad * 8];
            s = mfma16(ak1, bq1, s);
#pragma unroll
            for (int r = 0; r < 4; r++) {
                float ma = MASKED ? madd[t * 16 + quad * 4 + r] : 0.f;
                sv[t][r] = s[r] * 0.125f + ma;
            }
        }

        float vmax = sv[0][0];
#pragma unroll
        for (int t = 0; t < 4; t++)
#pragma unroll
            for (int r = 0; r < 4; r++) vmax = fmaxf(vmax, sv[t][r]);
        vmax = fmaxf(vmax, __shfl_xor(vmax, 16));
        vmax = fmaxf(vmax, __shfl_xor(vmax, 32));
        const float mnew  = fmaxf(mrun, vmax);
        const float alpha = __expf(mrun - mnew);
        mrun = mnew;
        float rsum = 0.f;
#pragma unroll
        for (int t = 0; t < 4; t++) {
            bf16x4 p4;
#pragma unroll
            for (int r = 0; r < 4; r++) {
                float p = __expf(sv[t][r] - mnew);
                rsum += p;
                p4[r] = (bf16)p;
            }
            *(bf16x4*)&Pt[wave][lrow][t * 16 + quad * 4] = p4;
        }
        rsum += __shfl_xor(rsum, 16);
        rsum += __shfl_xor(rsum, 32);
        lrun = lrun * alpha + rsum;

        float alpha4[4];
#pragma unroll
        for (int r = 0; r < 4; r++) alpha4[r] = __shfl(alpha, quad * 4 + r);
#pragma unroll
        for (int t = 0; t < 4; t++)
#pragma unroll
            for (int r = 0; r < 4; r++) acc[t][r] *= alpha4[r];

        __syncthreads();
        const bf16x8 ap0 = *(const bf16x8*)&Pt[wave][lrow][quad * 8];
        const bf16x8 ap1 = *(const bf16x8*)&Pt[wave][lrow][32 + quad * 8];

#pragma unroll
        for (int t = 0; t < 4; t++) {
            bf16x8 bv0 = *(const bf16x8*)&Vt[t * 16 + lrow][quad * 8];
            acc[t] = mfma16(ap0, bv0, acc[t]);
            bf16x8 bv1 = *(const bf16x8*)&Vt[t * 16 + lrow][32 + quad * 8];
            acc[t] = mfma16(ap1, bv1, acc[t]);
        }
    }

    float linv = 1.f / lrun;
    float linv4[4];
#pragma unroll
    for (int r = 0; r < 4; r++) linv4[r] = __shfl(linv, quad * 4 + r);
#pragma unroll
    for (int r = 0; r < 4; r++) {
        const size_t grow = (size_t)(b * N_ + q0 + quad * 4 + r);
#pragma unroll
        for (int t = 0; t < 4; t++)
            O[grow * C_ + h * 64 + t * 16 + lrow] = (bf16)(acc[t][r] * linv4[r]);
    }
}

// ---------------------------------------------------------------------------
extern "C" void kernel_launch(void* const* d_in, const int* in_sizes, int n_in,
                              void* d_out, int out_size, void* d_ws, size_t ws_size,
                              hipStream_t stream) {
    const float* x     = (const float*)d_in[0];
    const float* cdino = (const float*)d_in[1];
    const float* ctext = (const float*)d_in[2];
    const int*   tmask = (const int*)d_in[3];
    const float* W_ada = (const float*)d_in[4];
    const float* b_ada = (const float*)d_in[5];
    const float* W_qkv = (const float*)d_in[6];
    const float* b_qkv = (const float*)d_in[7];
    const float* W_sa  = (const float*)d_in[8];
    const float* b_sa  = (const float*)d_in[9];
    const float* W_q   = (const float*)d_in[10];
    const float* b_q   = (const float*)d_in[11];
    const float* W_kv  = (const float*)d_in[12];
    const float* b_kv  = (const float*)d_in[13];
    const float* W_ca  = (const float*)d_in[14];
    const float* b_ca  = (const float*)d_in[15];
    const float* W_fc1 = (const float*)d_in[16];
    const float* b_fc1 = (const float*)d_in[17];
    const float* W_fc2 = (const float*)d_in[18];
    const float* b_fc2 = (const float*)d_in[19];
    float* out = (float*)d_out;

    char* ws = (char*)d_ws;
    size_t off = 0;
    auto alloc = [&](size_t bytes) -> char* {
        char* p = ws + off;
        off += (bytes + 255) & ~(size_t)255;
        return p;
    };
    float* ada  = (float*)alloc((size_t)8 * 6144 * 4);
    bf16* ctxb  = (bf16*)alloc((size_t)1024 * 1024 * 2);
    bf16* WqkvT = (bf16*)alloc((size_t)3072 * 1024 * 2);
    bf16* WsaT  = (bf16*)alloc((size_t)1024 * 1024 * 2);
    bf16* WqT   = (bf16*)alloc((size_t)1024 * 1024 * 2);
    bf16* WkvT  = (bf16*)alloc((size_t)2048 * 1024 * 2);
    bf16* WcaT  = (bf16*)alloc((size_t)1024 * 1024 * 2);
    bf16* Wfc1T = (bf16*)alloc((size_t)4096 * 1024 * 2);
    bf16* Wfc2T = (bf16*)alloc((size_t)1024 * 4096 * 2);
    float* xbuf = (float*)alloc((size_t)8192 * 1024 * 4);
    bf16* hbuf  = (bf16*)alloc((size_t)8192 * 1024 * 2);
    bf16* attnb = (bf16*)alloc((size_t)8192 * 1024 * 2);
    bf16* VtgSA = (bf16*)alloc((size_t)8192 * 1024 * 2);
    bf16* VtgCA = (bf16*)alloc((size_t)8192 * 128 * 2);
    bf16* pool  = (bf16*)alloc((size_t)8192 * 4096 * 2);
    if (off > ws_size) return;

    bf16* qkvb  = pool;
    bf16* qb    = pool;
    bf16* kvb   = pool + (size_t)8192 * 1024;
    bf16* gelub = pool;

    // --- weight prep ---
    transpose_k<<<dim3(3072 / 32, 1024 / 32), 256, 0, stream>>>(W_qkv, WqkvT, 1024, 3072);
    transpose_k<<<dim3(1024 / 32, 1024 / 32), 256, 0, stream>>>(W_sa,  WsaT,  1024, 1024);
    transpose_k<<<dim3(1024 / 32, 1024 / 32), 256, 0, stream>>>(W_q,   WqT,   1024, 1024);
    transpose_k<<<dim3(2048 / 32, 1024 / 32), 256, 0, stream>>>(W_kv,  WkvT,  1024, 2048);
    transpose_k<<<dim3(1024 / 32, 1024 / 32), 256, 0, stream>>>(W_ca,  WcaT,  1024, 1024);
    transpose_k<<<dim3(4096 / 32, 1024 / 32), 256, 0, stream>>>(W_fc1, Wfc1T, 1024, 4096);
    transpose_k<<<dim3(1024 / 32, 4096 / 32), 256, 0, stream>>>(W_fc2, Wfc2T, 4096, 1024);
    cvt_bf16_k<<<1024, 256, 0, stream>>>(ctext, ctxb, 262144);

    // --- ada ---
    ada_init_k<<<192, 256, 0, stream>>>(b_ada, ada);
    ada_k<<<dim3(24, 32), 256, 0, stream>>>(cdino, W_ada, ada);

    // --- self-attention ---
    ln_mod_k<<<8192, 256, 0, stream>>>(x, ada, 0, 1024, hbuf);
    gemm_k<2, 1><<<24 * 64, 256, 0, stream>>>(hbuf, WqkvT, b_qkv, nullptr, nullptr, qkvb, 3072, 1024, 24);
    vtrans_k<<<dim3(32, 32, 8), 256, 0, stream>>>(qkvb, 3072, 2048, 1024, VtgSA);
    attn_k<false><<<dim3(16, 16, 8), 256, 0, stream>>>(qkvb, 3072, qkvb + 1024, 3072, VtgSA,
                                                       nullptr, 1024, attnb);
    gemm_k<1, 2><<<8 * 64, 512, 0, stream>>>(attnb, WsaT, b_sa, x, xbuf, nullptr, 1024, 1024, 8);

    // --- cross-attention ---
    ln_mod_k<<<8192, 256, 0, stream>>>(xbuf, ada, 2048, 3072, hbuf);
    gemm_k<2, 2><<<8 * 64, 512, 0, stream>>>(hbuf, WqT, b_q, nullptr, nullptr, qb, 1024, 1024, 8);
    gemm_k<2, 2><<<16 * 8, 512, 0, stream>>>(ctxb, WkvT, b_kv, nullptr, nullptr, kvb, 2048, 1024, 16);
    vtrans_k<<<dim3(4, 32, 8), 256, 0, stream>>>(kvb, 2048, 1024, 128, VtgCA);
    attn_k<true><<<dim3(16, 16, 8), 256, 0, stream>>>(qb, 1024, kvb, 2048, VtgCA,
                                                      tmask, 128, attnb);
    gemm_k<1, 2><<<8 * 64, 512, 0, stream>>>(attnb, WcaT, b_ca, xbuf, xbuf, nullptr, 1024, 1024, 8);

    // --- MLP ---
    ln_mod_k<<<8192, 256, 0, stream>>>(xbuf, ada, 4096, 5120, hbuf);
    gemm_k<3, 1><<<32 * 64, 256, 0, stream>>>(hbuf, Wfc1T, b_fc1, nullptr, nullptr, gelub, 4096, 1024, 32);
    gemm_k<1, 2><<<8 * 64, 512, 0, stream>>>(gelub, Wfc2T, b_fc2, xbuf, out, nullptr, 1024, 4096, 8);
}

// Round 6
// 711.919 us; speedup vs baseline: 1.4313x; 1.0444x over previous
//
#include <hip/hip_runtime.h>
#include <hip/hip_bf16.h>

// Problem constants
#define B_   8
#define N_   1024
#define M_   128
#define C_   1024
#define H_   16
#define D_   64
#define MLP_ 4096

typedef __bf16 bf16;
typedef __bf16 bf16x8 __attribute__((ext_vector_type(8)));
typedef __bf16 bf16x4 __attribute__((ext_vector_type(4)));
typedef float  f32x4  __attribute__((ext_vector_type(4)));

__device__ __forceinline__ f32x4 mfma16(bf16x8 a, bf16x8 b, f32x4 c) {
    return __builtin_amdgcn_mfma_f32_16x16x32_bf16(a, b, c, 0, 0, 0);
}

// async global->LDS, 16 B per lane (LDS dest wave-uniform base + lane*16)
__device__ __forceinline__ void gload16(const bf16* g, bf16* l) {
    __builtin_amdgcn_global_load_lds(
        (const __attribute__((address_space(1))) void*)g,
        (__attribute__((address_space(3))) void*)l, 16, 0, 0);
}

// ---------------------------------------------------------------------------
// Weight transpose + fp32->bf16:  W (K x Nc) fp32  ->  Wt (Nc x K) bf16
// ---------------------------------------------------------------------------
__global__ __launch_bounds__(256) void transpose_k(const float* __restrict__ W,
                                                   bf16* __restrict__ Wt,
                                                   int K, int Nc) {
    __shared__ float tile[32][33];
    const int x  = threadIdx.x & 31;
    const int y0 = threadIdx.x >> 5;
    const size_t n0 = (size_t)blockIdx.x * 32;
    const size_t k0 = (size_t)blockIdx.y * 32;
#pragma unroll
    for (int i = 0; i < 4; i++)
        tile[y0 + i * 8][x] = W[(k0 + y0 + i * 8) * Nc + n0 + x];
    __syncthreads();
#pragma unroll
    for (int i = 0; i < 4; i++)
        Wt[(n0 + y0 + i * 8) * K + k0 + x] = (bf16)tile[x][y0 + i * 8];
}

// bf16 V transpose: in rows (b*Mk + m), cols coff+hd -> outT[(b*1024+hd)*Mk + m]
__global__ __launch_bounds__(256) void vtrans_k(const bf16* __restrict__ in, int instride,
                                                int coff, int Mk, bf16* __restrict__ outT) {
    __shared__ bf16 t[32][33];
    const int tx = threadIdx.x & 31;
    const int ty0 = threadIdx.x >> 5;
    const int m0  = blockIdx.x * 32;
    const int hd0 = blockIdx.y * 32;
    const int b   = blockIdx.z;
#pragma unroll
    for (int i = 0; i < 4; i++)
        t[ty0 + i * 8][tx] = in[((size_t)(b * Mk + m0 + ty0 + i * 8)) * instride + coff + hd0 + tx];
    __syncthreads();
#pragma unroll
    for (int i = 0; i < 4; i++)
        outT[((size_t)(b * 1024 + hd0 + ty0 + i * 8)) * Mk + m0 + tx] = t[tx][ty0 + i * 8];
}

// fp32 -> bf16 elementwise (n4 = count/4)
__global__ __launch_bounds__(256) void cvt_bf16_k(const float* __restrict__ in,
                                                  bf16* __restrict__ out, int n4) {
    int i = blockIdx.x * 256 + threadIdx.x;
    if (i < n4) {
        float4 v = ((const float4*)in)[i];
        bf16x4 o;
        o[0] = (bf16)v.x; o[1] = (bf16)v.y; o[2] = (bf16)v.z; o[3] = (bf16)v.w;
        ((bf16x4*)out)[i] = o;
    }
}

// ---------------------------------------------------------------------------
// ada = silu(c_dino) @ W_ada + b_ada   (8 x 6144) fp32, split-K with atomics.
// ---------------------------------------------------------------------------
__global__ __launch_bounds__(256) void ada_init_k(const float* __restrict__ bias,
                                                  float* __restrict__ ada) {
    int i = blockIdx.x * 256 + threadIdx.x;
    ada[i] = bias[i % 6144];
}

__global__ __launch_bounds__(256) void ada_k(const float* __restrict__ cdino,
                                             const float* __restrict__ W,
                                             float* __restrict__ ada) {
    __shared__ float sc[8][32];
    const int tid = threadIdx.x;
    const int k0  = blockIdx.y * 32;
    {
        float c = cdino[(tid >> 5) * 1024 + k0 + (tid & 31)];
        sc[tid >> 5][tid & 31] = c / (1.f + __expf(-c));
    }
    __syncthreads();
    const int col = blockIdx.x * 256 + tid;
    float acc[8];
#pragma unroll
    for (int b = 0; b < 8; b++) acc[b] = 0.f;
    for (int kk = 0; kk < 32; kk++) {
        float w = W[(size_t)(k0 + kk) * 6144 + col];
#pragma unroll
        for (int b = 0; b < 8; b++) acc[b] += sc[b][kk] * w;
    }
#pragma unroll
    for (int b = 0; b < 8; b++) atomicAdd(&ada[(size_t)b * 6144 + col], acc[b]);
}

// ---------------------------------------------------------------------------
// h = modulate(LN(x), shift, scale)  -> bf16
// ---------------------------------------------------------------------------
__global__ __launch_bounds__(256) void ln_mod_k(const float* __restrict__ X,
                                                const float* __restrict__ ada,
                                                int shoff, int scoff,
                                                bf16* __restrict__ Hout) {
    const int row = blockIdx.x;
    const int b   = row >> 10;
    const int tid = threadIdx.x;
    const float4 v = ((const float4*)(X + (size_t)row * C_))[tid];
    float s  = v.x + v.y + v.z + v.w;
    float sq = v.x * v.x + v.y * v.y + v.z * v.z + v.w * v.w;
#pragma unroll
    for (int off = 32; off; off >>= 1) {
        s  += __shfl_xor(s,  off);
        sq += __shfl_xor(sq, off);
    }
    __shared__ float rs_[4], rq_[4];
    if ((tid & 63) == 0) { rs_[tid >> 6] = s; rq_[tid >> 6] = sq; }
    __syncthreads();
    s  = rs_[0] + rs_[1] + rs_[2] + rs_[3];
    sq = rq_[0] + rq_[1] + rq_[2] + rq_[3];
    const float mu   = s * (1.f / 1024.f);
    const float var  = sq * (1.f / 1024.f) - mu * mu;
    const float rstd = rsqrtf(var + 1e-6f);
    const float4 scv = ((const float4*)(ada + (size_t)b * 6144 + scoff))[tid];
    const float4 shv = ((const float4*)(ada + (size_t)b * 6144 + shoff))[tid];
    bf16x4 o;
    o[0] = (bf16)(((v.x - mu) * rstd) * (1.f + scv.x) + shv.x);
    o[1] = (bf16)(((v.y - mu) * rstd) * (1.f + scv.y) + shv.y);
    o[2] = (bf16)(((v.z - mu) * rstd) * (1.f + scv.z) + shv.z);
    o[3] = (bf16)(((v.w - mu) * rstd) * (1.f + scv.w) + shv.w);
    *(bf16x4*)(Hout + (size_t)row * C_ + tid * 4) = o;
}

// ---------------------------------------------------------------------------
// Generic bf16 MFMA GEMM: m97 structure + LDS XOR swizzle + XCD-local grid
// + in-block split-K (KS) + DOUBLE-BUFFERED K-loop.
// Per iter: sync -> issue next-iter global_load_lds into buf p^1 -> MFMA on
// buf p. The barrier's vmcnt(0) drain now lands AFTER a full MFMA phase of
// flight time for the staged loads -> load latency hidden per-wave even at
// 2 blocks/CU. One barrier per iteration instead of two.
// MODE 1: fp32 out = v + resid    MODE 2: bf16 out = v    MODE 3: bf16 gelu(v)
// ---------------------------------------------------------------------------
template <int MODE, int KS>
__global__ __launch_bounds__(256 * KS) void gemm_k(const bf16* __restrict__ A,
                                                   const bf16* __restrict__ Bt,
                                                   const float* __restrict__ bias,
                                                   const float* resid,
                                                   float* outF, bf16* outB,
                                                   int Ncols, int K, int GX) {
    __shared__ __attribute__((aligned(16))) bf16 As[2][KS][128][32];
    __shared__ __attribute__((aligned(16))) bf16 Bs[2][KS][128][32];
    const int tid  = threadIdx.x & 255;     // within-group thread id
    const int grp  = threadIdx.x >> 8;      // k-group (0..KS-1)
    const int lane = tid & 63, wave = tid >> 6;
    const int lrow = lane & 15, quad = lane >> 4;
    const int wm = wave >> 1, wn = wave & 1;

    // XCD-locality block swizzle
    const unsigned lid = blockIdx.x;
    const unsigned xcd = lid & 7, s = lid >> 3;
    const unsigned bnb = s % GX, bmb = (s / GX) * 8 + xcd;
    const size_t bm = (size_t)bmb * 128;
    const size_t bn = (size_t)bnb * 128;

    const int Kh = K / KS;                  // per-group K extent
    // staging: physical (prow, pseg) holds global k-seg pseg ^ ((prow>>1)&3)
    const int prow = tid >> 2, pseg = tid & 3;
    const int gseg = pseg ^ ((prow >> 1) & 3);
    const bf16* gA0 = A  + (bm + prow) * (size_t)K + grp * Kh + gseg * 8;
    const bf16* gA1 = gA0 + (size_t)64 * K;
    const bf16* gB0 = Bt + (bn + prow) * (size_t)K + grp * Kh + gseg * 8;
    const bf16* gB1 = gB0 + (size_t)64 * K;
    const int bufoff = KS * 128 * 32;       // elements per buffer
    bf16* lA = &As[0][grp][0][0] + wave * 512;
    bf16* lB = &Bs[0][grp][0][0] + wave * 512;

    // read-side swizzled chunk offset
    const int xoff = (quad ^ ((lrow >> 1) & 3)) * 8;

    f32x4 acc[4][4];
#pragma unroll
    for (int i = 0; i < 4; i++)
#pragma unroll
        for (int j = 0; j < 4; j++) acc[i][j] = (f32x4){0.f, 0.f, 0.f, 0.f};

    // prologue: stage iter 0 into buf 0
    {
        gload16(gA0, lA);
        gload16(gA1, lA + 2048);
        gload16(gB0, lB);
        gload16(gB1, lB + 2048);
    }
    int p = 0;
    for (int ko = 0; ko < Kh; ko += 32) {
        __syncthreads();                    // buf p staged (drain had MFMA phase in flight)
        if (ko + 32 < Kh) {                 // prefetch next iter into buf p^1
            const int po = (p ^ 1) * bufoff;
            gload16(gA0 + ko + 32, lA + po);
            gload16(gA1 + ko + 32, lA + po + 2048);
            gload16(gB0 + ko + 32, lB + po);
            gload16(gB1 + ko + 32, lB + po + 2048);
        }
        const bf16(*Asp)[32] = As[p][grp];
        const bf16(*Bsp)[32] = Bs[p][grp];
        bf16x8 af[4], bfr[4];
#pragma unroll
        for (int mi = 0; mi < 4; mi++)
            af[mi] = *(const bf16x8*)&Asp[wm * 64 + mi * 16 + lrow][xoff];
#pragma unroll
        for (int ni = 0; ni < 4; ni++)
            bfr[ni] = *(const bf16x8*)&Bsp[wn * 64 + ni * 16 + lrow][xoff];
#pragma unroll
        for (int mi = 0; mi < 4; mi++)
#pragma unroll
            for (int ni = 0; ni < 4; ni++)
                acc[mi][ni] = mfma16(af[mi], bfr[ni], acc[mi][ni]);
        p ^= 1;
    }

    // in-block split-K reduction: group 1 -> LDS (As region) -> group 0.
    if constexpr (KS == 2) {
        f32x4* red = (f32x4*)&As[0][0][0][0];   // 16 KB region
#pragma unroll
        for (int rnd = 0; rnd < 4; rnd++) {
            __syncthreads();
            if (grp == 1) {
#pragma unroll
                for (int c = 0; c < 4; c++) {
                    const int idx = rnd * 4 + c;
                    red[c * 256 + tid] = acc[idx >> 2][idx & 3];
                }
            }
            __syncthreads();
            if (grp == 0) {
#pragma unroll
                for (int c = 0; c < 4; c++) {
                    const int idx = rnd * 4 + c;
                    acc[idx >> 2][idx & 3] += red[c * 256 + tid];
                }
            }
        }
    }

    if (grp == 0) {
#pragma unroll
        for (int mi = 0; mi < 4; mi++) {
#pragma unroll
            for (int ni = 0; ni < 4; ni++) {
                const size_t gcol = bn + wn * 64 + ni * 16 + lrow;
                const float bv = bias[gcol];
#pragma unroll
                for (int r = 0; r < 4; r++) {
                    const size_t grow = bm + wm * 64 + mi * 16 + quad * 4 + r;
                    const size_t idx  = grow * Ncols + gcol;
                    float v = acc[mi][ni][r] + bv;
                    if (MODE == 1) {
                        outF[idx] = v + resid[idx];
                    } else if (MODE == 2) {
                        outB[idx] = (bf16)v;
                    } else {
                        float z = 1.59576912f * (v + 0.044715f * v * v * v);
                        outB[idx] = (bf16)(v / (1.f + __expf(-z)));
                    }
                }
            }
        }
    }
}

// ---------------------------------------------------------------------------
// Flash attention, S^T formulation. D=64, 64-key chunks. (unchanged)
// ---------------------------------------------------------------------------
template <bool MASKED>
__global__ __launch_bounds__(256) void attn_k(const bf16* __restrict__ Qp, int qstride,
                                              const bf16* __restrict__ Kp, int kstride,
                                              const bf16* __restrict__ Vtg,
                                              const int* __restrict__ mask, int Mk,
                                              bf16* __restrict__ O) {
    __shared__ __attribute__((aligned(16))) bf16 Kt[64][88];      // [key][d]
    __shared__ __attribute__((aligned(16))) bf16 Vt[64][88];      // [d][key]
    __shared__ __attribute__((aligned(16))) bf16 Pt[4][16][88];   // [wave][q][key]
    __shared__ float madd[64];

    const int b = blockIdx.z, h = blockIdx.y;
    const int tid  = threadIdx.x;
    const int lane = tid & 63, wave = tid >> 6;
    const int lrow = lane & 15, quad = lane >> 4;
    const int q0 = blockIdx.x * 64 + wave * 16;

    const bf16* qp = Qp + ((size_t)(b * N_ + q0 + lrow)) * qstride + h * 64 + quad * 8;
    const bf16x8 bq0 = *(const bf16x8*)(qp);
    const bf16x8 bq1 = *(const bf16x8*)(qp + 32);

    f32x4 acc[4];
#pragma unroll
    for (int t = 0; t < 4; t++) acc[t] = (f32x4){0.f, 0.f, 0.f, 0.f};
    float mrun = -3e38f, lrun = 0.f;

    const int srow = tid >> 2;
    const int sseg = (tid & 3) * 16;

    const bf16* kbase = Kp + ((size_t)b * Mk + srow) * kstride + h * 64 + sseg;
    const bf16* vbase = Vtg + ((size_t)(b * 1024 + h * 64 + srow)) * Mk + sseg;

    for (int kc = 0; kc < Mk; kc += 64) {
        __syncthreads();
        const bf16* kp = kbase + (size_t)kc * kstride;
        bf16x8 k0 = *(const bf16x8*)kp;
        bf16x8 k1 = *(const bf16x8*)(kp + 8);
        *(bf16x8*)&Kt[srow][sseg]     = k0;
        *(bf16x8*)&Kt[srow][sseg + 8] = k1;
        const bf16* vp = vbase + kc;
        bf16x8 v0 = *(const bf16x8*)vp;
        bf16x8 v1 = *(const bf16x8*)(vp + 8);
        *(bf16x8*)&Vt[srow][sseg]     = v0;
        *(bf16x8*)&Vt[srow][sseg + 8] = v1;
        if (MASKED && tid < 64)
            madd[tid] = (mask[b * Mk + kc + tid] == 0) ? -1e30f : 0.f;
        __syncthreads();

        float sv[4][4];
#pragma unroll
        for (int t = 0; t < 4; t++) {
            f32x4 s = (f32x4){0.f, 0.f, 0.f, 0.f};
            bf16x8 ak0 = *(const bf16x8*)&Kt[t * 16 + lrow][quad * 8];
            s = mfma16(ak0, bq0, s);
            bf16x8 ak1 = *(const bf16x8*)&Kt[t * 16 + lrow][32 + quad * 8];
            s = mfma16(ak1, bq1, s);
#pragma unroll
            for (int r = 0; r < 4; r++) {
                float ma = MASKED ? madd[t * 16 + quad * 4 + r] : 0.f;
                sv[t][r] = s[r] * 0.125f + ma;
            }
        }

        float vmax = sv[0][0];
#pragma unroll
        for (int t = 0; t < 4; t++)
#pragma unroll
            for (int r = 0; r < 4; r++) vmax = fmaxf(vmax, sv[t][r]);
        vmax = fmaxf(vmax, __shfl_xor(vmax, 16));
        vmax = fmaxf(vmax, __shfl_xor(vmax, 32));
        const float mnew  = fmaxf(mrun, vmax);
        const float alpha = __expf(mrun - mnew);
        mrun = mnew;
        float rsum = 0.f;
#pragma unroll
        for (int t = 0; t < 4; t++) {
            bf16x4 p4;
#pragma unroll
            for (int r = 0; r < 4; r++) {
                float p = __expf(sv[t][r] - mnew);
                rsum += p;
                p4[r] = (bf16)p;
            }
            *(bf16x4*)&Pt[wave][lrow][t * 16 + quad * 4] = p4;
        }
        rsum += __shfl_xor(rsum, 16);
        rsum += __shfl_xor(rsum, 32);
        lrun = lrun * alpha + rsum;

        float alpha4[4];
#pragma unroll
        for (int r = 0; r < 4; r++) alpha4[r] = __shfl(alpha, quad * 4 + r);
#pragma unroll
        for (int t = 0; t < 4; t++)
#pragma unroll
            for (int r = 0; r < 4; r++) acc[t][r] *= alpha4[r];

        __syncthreads();
        const bf16x8 ap0 = *(const bf16x8*)&Pt[wave][lrow][quad * 8];
        const bf16x8 ap1 = *(const bf16x8*)&Pt[wave][lrow][32 + quad * 8];

#pragma unroll
        for (int t = 0; t < 4; t++) {
            bf16x8 bv0 = *(const bf16x8*)&Vt[t * 16 + lrow][quad * 8];
            acc[t] = mfma16(ap0, bv0, acc[t]);
            bf16x8 bv1 = *(const bf16x8*)&Vt[t * 16 + lrow][32 + quad * 8];
            acc[t] = mfma16(ap1, bv1, acc[t]);
        }
    }

    float linv = 1.f / lrun;
    float linv4[4];
#pragma unroll
    for (int r = 0; r < 4; r++) linv4[r] = __shfl(linv, quad * 4 + r);
#pragma unroll
    for (int r = 0; r < 4; r++) {
        const size_t grow = (size_t)(b * N_ + q0 + quad * 4 + r);
#pragma unroll
        for (int t = 0; t < 4; t++)
            O[grow * C_ + h * 64 + t * 16 + lrow] = (bf16)(acc[t][r] * linv4[r]);
    }
}

// ---------------------------------------------------------------------------
extern "C" void kernel_launch(void* const* d_in, const int* in_sizes, int n_in,
                              void* d_out, int out_size, void* d_ws, size_t ws_size,
                              hipStream_t stream) {
    const float* x     = (const float*)d_in[0];
    const float* cdino = (const float*)d_in[1];
    const float* ctext = (const float*)d_in[2];
    const int*   tmask = (const int*)d_in[3];
    const float* W_ada = (const float*)d_in[4];
    const float* b_ada = (const float*)d_in[5];
    const float* W_qkv = (const float*)d_in[6];
    const float* b_qkv = (const float*)d_in[7];
    const float* W_sa  = (const float*)d_in[8];
    const float* b_sa  = (const float*)d_in[9];
    const float* W_q   = (const float*)d_in[10];
    const float* b_q   = (const float*)d_in[11];
    const float* W_kv  = (const float*)d_in[12];
    const float* b_kv  = (const float*)d_in[13];
    const float* W_ca  = (const float*)d_in[14];
    const float* b_ca  = (const float*)d_in[15];
    const float* W_fc1 = (const float*)d_in[16];
    const float* b_fc1 = (const float*)d_in[17];
    const float* W_fc2 = (const float*)d_in[18];
    const float* b_fc2 = (const float*)d_in[19];
    float* out = (float*)d_out;

    char* ws = (char*)d_ws;
    size_t off = 0;
    auto alloc = [&](size_t bytes) -> char* {
        char* p = ws + off;
        off += (bytes + 255) & ~(size_t)255;
        return p;
    };
    float* ada  = (float*)alloc((size_t)8 * 6144 * 4);
    bf16* ctxb  = (bf16*)alloc((size_t)1024 * 1024 * 2);
    bf16* WqkvT = (bf16*)alloc((size_t)3072 * 1024 * 2);
    bf16* WsaT  = (bf16*)alloc((size_t)1024 * 1024 * 2);
    bf16* WqT   = (bf16*)alloc((size_t)1024 * 1024 * 2);
    bf16* WkvT  = (bf16*)alloc((size_t)2048 * 1024 * 2);
    bf16* WcaT  = (bf16*)alloc((size_t)1024 * 1024 * 2);
    bf16* Wfc1T = (bf16*)alloc((size_t)4096 * 1024 * 2);
    bf16* Wfc2T = (bf16*)alloc((size_t)1024 * 4096 * 2);
    float* xbuf = (float*)alloc((size_t)8192 * 1024 * 4);
    bf16* hbuf  = (bf16*)alloc((size_t)8192 * 1024 * 2);
    bf16* attnb = (bf16*)alloc((size_t)8192 * 1024 * 2);
    bf16* VtgSA = (bf16*)alloc((size_t)8192 * 1024 * 2);
    bf16* VtgCA = (bf16*)alloc((size_t)8192 * 128 * 2);
    bf16* pool  = (bf16*)alloc((size_t)8192 * 4096 * 2);
    if (off > ws_size) return;

    bf16* qkvb  = pool;
    bf16* qb    = pool;
    bf16* kvb   = pool + (size_t)8192 * 1024;
    bf16* gelub = pool;

    // --- weight prep ---
    transpose_k<<<dim3(3072 / 32, 1024 / 32), 256, 0, stream>>>(W_qkv, WqkvT, 1024, 3072);
    transpose_k<<<dim3(1024 / 32, 1024 / 32), 256, 0, stream>>>(W_sa,  WsaT,  1024, 1024);
    transpose_k<<<dim3(1024 / 32, 1024 / 32), 256, 0, stream>>>(W_q,   WqT,   1024, 1024);
    transpose_k<<<dim3(2048 / 32, 1024 / 32), 256, 0, stream>>>(W_kv,  WkvT,  1024, 2048);
    transpose_k<<<dim3(1024 / 32, 1024 / 32), 256, 0, stream>>>(W_ca,  WcaT,  1024, 1024);
    transpose_k<<<dim3(4096 / 32, 1024 / 32), 256, 0, stream>>>(W_fc1, Wfc1T, 1024, 4096);
    transpose_k<<<dim3(1024 / 32, 4096 / 32), 256, 0, stream>>>(W_fc2, Wfc2T, 4096, 1024);
    cvt_bf16_k<<<1024, 256, 0, stream>>>(ctext, ctxb, 262144);

    // --- ada ---
    ada_init_k<<<192, 256, 0, stream>>>(b_ada, ada);
    ada_k<<<dim3(24, 32), 256, 0, stream>>>(cdino, W_ada, ada);

    // --- self-attention ---
    ln_mod_k<<<8192, 256, 0, stream>>>(x, ada, 0, 1024, hbuf);
    gemm_k<2, 1><<<24 * 64, 256, 0, stream>>>(hbuf, WqkvT, b_qkv, nullptr, nullptr, qkvb, 3072, 1024, 24);
    vtrans_k<<<dim3(32, 32, 8), 256, 0, stream>>>(qkvb, 3072, 2048, 1024, VtgSA);
    attn_k<false><<<dim3(16, 16, 8), 256, 0, stream>>>(qkvb, 3072, qkvb + 1024, 3072, VtgSA,
                                                       nullptr, 1024, attnb);
    gemm_k<1, 2><<<8 * 64, 512, 0, stream>>>(attnb, WsaT, b_sa, x, xbuf, nullptr, 1024, 1024, 8);

    // --- cross-attention ---
    ln_mod_k<<<8192, 256, 0, stream>>>(xbuf, ada, 2048, 3072, hbuf);
    gemm_k<2, 2><<<8 * 64, 512, 0, stream>>>(hbuf, WqT, b_q, nullptr, nullptr, qb, 1024, 1024, 8);
    gemm_k<2, 2><<<16 * 8, 512, 0, stream>>>(ctxb, WkvT, b_kv, nullptr, nullptr, kvb, 2048, 1024, 16);
    vtrans_k<<<dim3(4, 32, 8), 256, 0, stream>>>(kvb, 2048, 1024, 128, VtgCA);
    attn_k<true><<<dim3(16, 16, 8), 256, 0, stream>>>(qb, 1024, kvb, 2048, VtgCA,
                                                      tmask, 128, attnb);
    gemm_k<1, 2><<<8 * 64, 512, 0, stream>>>(attnb, WcaT, b_ca, xbuf, xbuf, nullptr, 1024, 1024, 8);

    // --- MLP ---
    ln_mod_k<<<8192, 256, 0, stream>>>(xbuf, ada, 4096, 5120, hbuf);
    gemm_k<3, 1><<<32 * 64, 256, 0, stream>>>(hbuf, Wfc1T, b_fc1, nullptr, nullptr, gelub, 4096, 1024, 32);
    gemm_k<1, 2><<<8 * 64, 512, 0, stream>>>(gelub, Wfc2T, b_fc2, xbuf, out, nullptr, 1024, 4096, 8);
}